// Round 9
// baseline (1771.670 us; speedup 1.0000x reference)
//
#include <hip/hip_runtime.h>
#include <math.h>

// Problem constants
#define B_TOT   2048
#define N_IN    1024
#define N_H     1024
#define N_OUT   512
#define N_UPD   1536
#define T_TOT   3072   // MAX_STEPS * N_UPD
#define N_WIN   48     // T_TOT / 64

// ---------------- prep kernels ----------------

// W1T[c*1024 + r] = W1[r*1024 + c]
__global__ void prep_w1t(const float* __restrict__ W1, float* __restrict__ W1T) {
    int idx = blockIdx.x * 256 + threadIdx.x;   // < 1024*1024
    int r = idx & 1023;
    int c = idx >> 10;
    W1T[(size_t)c * 1024 + r] = W1[(size_t)r * 1024 + c];
}

// W2Tf[c*512 + r] = W2[r*1024 + c]
__global__ void prep_w2tf(const float* __restrict__ W2, float* __restrict__ W2Tf) {
    int idx = blockIdx.x * 256 + threadIdx.x;   // < 512*1024
    int r = idx & 511;
    int c = idx >> 9;
    W2Tf[(size_t)c * 512 + r] = W2[(size_t)r * 1024 + c];
}

// WHf[n][lane][j] = W2[(j*64+lane)][n]   (hidden-flip fragment, fp32, j fast 0..7)
__global__ void prep_whf(const float* __restrict__ W2, float* __restrict__ WHf) {
    int idx = blockIdx.x * 256 + threadIdx.x;   // < 1024*512
    int n = idx >> 9;
    int r = idx & 511;
    int l = r >> 3, j = r & 7;
    WHf[idx] = W2[(size_t)(j * 64 + l) * 1024 + n];
}

// WOf[nn][lane][j] = W2[nn][j*64+lane]   (output-flip fragment, fp32, j fast 0..15)
__global__ void prep_wof(const float* __restrict__ W2, float* __restrict__ WOf) {
    int idx = blockIdx.x * 256 + threadIdx.x;   // < 512*1024
    int nn = idx >> 10;
    int r = idx & 1023;
    int l = r >> 4, j = r & 15;
    WOf[idx] = W2[(size_t)nn * 1024 + j * 64 + l];
}

// WXf[w][j][l]: fp32 coupling of flip at step w*64+j onto decision at step w*64+l.
__global__ void prep_wx(const float* __restrict__ W2, const int* __restrict__ ids,
                        float* __restrict__ WXf) {
    int idx = blockIdx.x * 256 + threadIdx.x;   // < 48*4096
    int w = idx >> 12;
    int j = (idx >> 6) & 63;
    int l = idx & 63;
    int mj = ids[w * 64 + j];
    int nl = ids[w * 64 + l];
    float v = 0.0f;
    if (mj < N_H && nl >= N_H) v = W2[(size_t)(nl - N_H) * 1024 + mj];
    else if (mj >= N_H && nl < N_H) v = W2[(size_t)(mj - N_H) * 1024 + nl];
    WXf[idx] = v;
}

// posA[n] = sweep-1 step of unit n; posB[n] = sweep-2 step - 1536
__global__ void prep_pos(const int* __restrict__ ids, int* __restrict__ posA,
                         int* __restrict__ posB) {
    int t = blockIdx.x * 256 + threadIdx.x;   // < 3072
    int n = ids[t];
    if (t < N_UPD) posA[n] = t; else posB[n] = t - N_UPD;
}

// pos2[t] = posA[ids[1536 + t]]  (coalesced sweep-2 old-state locator)
__global__ void prep_pos2(const int* __restrict__ ids, const int* __restrict__ posA,
                          int* __restrict__ pos2) {
    int t = blockIdx.x * 256 + threadIdx.x;   // < 1536
    pos2[t] = posA[ids[N_UPD + t]];
}

// thT[b][t] = T(t) * (log(u[t][b]) - log1p(-u[t][b]))  in f64 — EXACT same
// expression/order as the previously-passing in-gibbs computation.
__global__ __launch_bounds__(256) void prep_th(const float* __restrict__ u,
                                               double* __restrict__ thT) {
    __shared__ double tile[64][65];
    int bt = blockIdx.x % 48;     // t tile
    int bb = blockIdx.x / 48;     // b tile
    int tx = threadIdx.x & 63;
    int ty0 = threadIdx.x >> 6;   // 0..3
    const double T1c = (double)(float)(2.0 / exp((double)1 / 5.0));
    for (int r = ty0; r < 64; r += 4) {
        int t = bt * 64 + r;
        double ud = (double)u[(size_t)t * 2048 + bb * 64 + tx];
        double T = (t >= N_UPD) ? T1c : 2.0;
        tile[r][tx] = T * (log(ud) - log1p(-ud));
    }
    __syncthreads();
    for (int r = ty0; r < 64; r += 4)
        thT[(size_t)(bb * 64 + r) * 3072 + bt * 64 + tx] = tile[tx][r];
}

// out[b][0:1024] = x[b][:]
__global__ void copy_x(const float* __restrict__ x, float* __restrict__ out) {
    int idx = blockIdx.x * 256 + threadIdx.x;   // < 2048*256 (float4 units)
    int b = idx >> 8, c = idx & 255;
    ((float4*)(out + (size_t)b * 2560))[c] = ((const float4*)(x + (size_t)b * 1024))[c];
}

// ---------------- init fields (fp64) ----------------------------------------
// Branch-free accumulate: acc_r = fma(bit?1.0:0.0, dw, acc_r)  (bit-identical).

#define FMA32(M, DW) { \
    a0  = fma(((M) & 0x00000001u) ? 1.0 : 0.0, (DW), a0 ); \
    a1  = fma(((M) & 0x00000002u) ? 1.0 : 0.0, (DW), a1 ); \
    a2  = fma(((M) & 0x00000004u) ? 1.0 : 0.0, (DW), a2 ); \
    a3  = fma(((M) & 0x00000008u) ? 1.0 : 0.0, (DW), a3 ); \
    a4  = fma(((M) & 0x00000010u) ? 1.0 : 0.0, (DW), a4 ); \
    a5  = fma(((M) & 0x00000020u) ? 1.0 : 0.0, (DW), a5 ); \
    a6  = fma(((M) & 0x00000040u) ? 1.0 : 0.0, (DW), a6 ); \
    a7  = fma(((M) & 0x00000080u) ? 1.0 : 0.0, (DW), a7 ); \
    a8  = fma(((M) & 0x00000100u) ? 1.0 : 0.0, (DW), a8 ); \
    a9  = fma(((M) & 0x00000200u) ? 1.0 : 0.0, (DW), a9 ); \
    a10 = fma(((M) & 0x00000400u) ? 1.0 : 0.0, (DW), a10); \
    a11 = fma(((M) & 0x00000800u) ? 1.0 : 0.0, (DW), a11); \
    a12 = fma(((M) & 0x00001000u) ? 1.0 : 0.0, (DW), a12); \
    a13 = fma(((M) & 0x00002000u) ? 1.0 : 0.0, (DW), a13); \
    a14 = fma(((M) & 0x00004000u) ? 1.0 : 0.0, (DW), a14); \
    a15 = fma(((M) & 0x00008000u) ? 1.0 : 0.0, (DW), a15); \
    a16 = fma(((M) & 0x00010000u) ? 1.0 : 0.0, (DW), a16); \
    a17 = fma(((M) & 0x00020000u) ? 1.0 : 0.0, (DW), a17); \
    a18 = fma(((M) & 0x00040000u) ? 1.0 : 0.0, (DW), a18); \
    a19 = fma(((M) & 0x00080000u) ? 1.0 : 0.0, (DW), a19); \
    a20 = fma(((M) & 0x00100000u) ? 1.0 : 0.0, (DW), a20); \
    a21 = fma(((M) & 0x00200000u) ? 1.0 : 0.0, (DW), a21); \
    a22 = fma(((M) & 0x00400000u) ? 1.0 : 0.0, (DW), a22); \
    a23 = fma(((M) & 0x00800000u) ? 1.0 : 0.0, (DW), a23); \
    a24 = fma(((M) & 0x01000000u) ? 1.0 : 0.0, (DW), a24); \
    a25 = fma(((M) & 0x02000000u) ? 1.0 : 0.0, (DW), a25); \
    a26 = fma(((M) & 0x04000000u) ? 1.0 : 0.0, (DW), a26); \
    a27 = fma(((M) & 0x08000000u) ? 1.0 : 0.0, (DW), a27); \
    a28 = fma(((M) & 0x10000000u) ? 1.0 : 0.0, (DW), a28); \
    a29 = fma(((M) & 0x20000000u) ? 1.0 : 0.0, (DW), a29); \
    a30 = fma(((M) & 0x40000000u) ? 1.0 : 0.0, (DW), a30); \
    a31 = fma(((M) & 0x80000000u) ? 1.0 : 0.0, (DW), a31); }

#define FMA16(M, DW) { \
    a0  = fma(((M) & 0x0001u) ? 1.0 : 0.0, (DW), a0 ); \
    a1  = fma(((M) & 0x0002u) ? 1.0 : 0.0, (DW), a1 ); \
    a2  = fma(((M) & 0x0004u) ? 1.0 : 0.0, (DW), a2 ); \
    a3  = fma(((M) & 0x0008u) ? 1.0 : 0.0, (DW), a3 ); \
    a4  = fma(((M) & 0x0010u) ? 1.0 : 0.0, (DW), a4 ); \
    a5  = fma(((M) & 0x0020u) ? 1.0 : 0.0, (DW), a5 ); \
    a6  = fma(((M) & 0x0040u) ? 1.0 : 0.0, (DW), a6 ); \
    a7  = fma(((M) & 0x0080u) ? 1.0 : 0.0, (DW), a7 ); \
    a8  = fma(((M) & 0x0100u) ? 1.0 : 0.0, (DW), a8 ); \
    a9  = fma(((M) & 0x0200u) ? 1.0 : 0.0, (DW), a9 ); \
    a10 = fma(((M) & 0x0400u) ? 1.0 : 0.0, (DW), a10); \
    a11 = fma(((M) & 0x0800u) ? 1.0 : 0.0, (DW), a11); \
    a12 = fma(((M) & 0x1000u) ? 1.0 : 0.0, (DW), a12); \
    a13 = fma(((M) & 0x2000u) ? 1.0 : 0.0, (DW), a13); \
    a14 = fma(((M) & 0x4000u) ? 1.0 : 0.0, (DW), a14); \
    a15 = fma(((M) & 0x8000u) ? 1.0 : 0.0, (DW), a15); }

// h1[b,n] = b1[n] + sum_i x[b,i] W1T[i,n] + sum_o s2[b,o] W2[o,n]
__global__ __launch_bounds__(256) void init_h1(
    const float* __restrict__ x, const float* __restrict__ s2i,
    const float* __restrict__ W1T, const float* __restrict__ W2,
    const float* __restrict__ b1, double* __restrict__ h1g)
{
    const int tid = threadIdx.x;
    const int ug  = blockIdx.x & 3;          // unit group (4 x 256)
    const int b0  = (blockIdx.x >> 2) << 5;  // row group base (32 rows)
    const int n   = (ug << 8) + tid;

    __shared__ unsigned xm[1024];
    __shared__ unsigned s2m[512];

    for (int i = tid; i < 1024; i += 256) {
        unsigned m = 0;
        #pragma unroll
        for (int bb = 0; bb < 32; ++bb)
            m |= (x[(size_t)(b0 + bb) * 1024 + i] != 0.0f) ? (1u << bb) : 0u;
        xm[i] = m;
    }
    for (int j = tid; j < 512; j += 256) {
        unsigned m = 0;
        #pragma unroll
        for (int bb = 0; bb < 32; ++bb)
            m |= (s2i[(size_t)(b0 + bb) * 512 + j] != 0.0f) ? (1u << bb) : 0u;
        s2m[j] = m;
    }
    __syncthreads();

    double a0, a1, a2, a3, a4, a5, a6, a7, a8, a9, a10, a11, a12, a13, a14, a15,
           a16, a17, a18, a19, a20, a21, a22, a23, a24, a25, a26, a27, a28, a29,
           a30, a31;
    {
        double bv = (double)b1[n];
        a0 = bv; a1 = bv; a2 = bv; a3 = bv; a4 = bv; a5 = bv; a6 = bv; a7 = bv;
        a8 = bv; a9 = bv; a10 = bv; a11 = bv; a12 = bv; a13 = bv; a14 = bv; a15 = bv;
        a16 = bv; a17 = bv; a18 = bv; a19 = bv; a20 = bv; a21 = bv; a22 = bv; a23 = bv;
        a24 = bv; a25 = bv; a26 = bv; a27 = bv; a28 = bv; a29 = bv; a30 = bv; a31 = bv;
    }

    {
        float wc0, wc1, wc2, wc3, wc4, wc5, wc6, wc7;
        {
            const float* q = W1T + n;
            wc0 = q[0];    wc1 = q[1024]; wc2 = q[2048]; wc3 = q[3072];
            wc4 = q[4096]; wc5 = q[5120]; wc6 = q[6144]; wc7 = q[7168];
        }
        for (int i0 = 0; i0 < 1024; i0 += 8) {
            float wn0, wn1, wn2, wn3, wn4, wn5, wn6, wn7;
            if (i0 + 8 < 1024) {
                const float* q = W1T + (size_t)(i0 + 8) * 1024 + n;
                wn0 = q[0];    wn1 = q[1024]; wn2 = q[2048]; wn3 = q[3072];
                wn4 = q[4096]; wn5 = q[5120]; wn6 = q[6144]; wn7 = q[7168];
            } else {
                wn0 = wc0; wn1 = wc1; wn2 = wc2; wn3 = wc3;
                wn4 = wc4; wn5 = wc5; wn6 = wc6; wn7 = wc7;
            }
            unsigned m0 = (unsigned)__builtin_amdgcn_readfirstlane((int)xm[i0 + 0]);
            unsigned m1 = (unsigned)__builtin_amdgcn_readfirstlane((int)xm[i0 + 1]);
            unsigned m2 = (unsigned)__builtin_amdgcn_readfirstlane((int)xm[i0 + 2]);
            unsigned m3 = (unsigned)__builtin_amdgcn_readfirstlane((int)xm[i0 + 3]);
            unsigned m4 = (unsigned)__builtin_amdgcn_readfirstlane((int)xm[i0 + 4]);
            unsigned m5 = (unsigned)__builtin_amdgcn_readfirstlane((int)xm[i0 + 5]);
            unsigned m6 = (unsigned)__builtin_amdgcn_readfirstlane((int)xm[i0 + 6]);
            unsigned m7 = (unsigned)__builtin_amdgcn_readfirstlane((int)xm[i0 + 7]);
            double dw;
            dw = (double)wc0; FMA32(m0, dw);
            dw = (double)wc1; FMA32(m1, dw);
            dw = (double)wc2; FMA32(m2, dw);
            dw = (double)wc3; FMA32(m3, dw);
            dw = (double)wc4; FMA32(m4, dw);
            dw = (double)wc5; FMA32(m5, dw);
            dw = (double)wc6; FMA32(m6, dw);
            dw = (double)wc7; FMA32(m7, dw);
            wc0 = wn0; wc1 = wn1; wc2 = wn2; wc3 = wn3;
            wc4 = wn4; wc5 = wn5; wc6 = wn6; wc7 = wn7;
        }
    }
    {
        float wc0, wc1, wc2, wc3, wc4, wc5, wc6, wc7;
        {
            const float* q = W2 + n;
            wc0 = q[0];    wc1 = q[1024]; wc2 = q[2048]; wc3 = q[3072];
            wc4 = q[4096]; wc5 = q[5120]; wc6 = q[6144]; wc7 = q[7168];
        }
        for (int i0 = 0; i0 < 512; i0 += 8) {
            float wn0, wn1, wn2, wn3, wn4, wn5, wn6, wn7;
            if (i0 + 8 < 512) {
                const float* q = W2 + (size_t)(i0 + 8) * 1024 + n;
                wn0 = q[0];    wn1 = q[1024]; wn2 = q[2048]; wn3 = q[3072];
                wn4 = q[4096]; wn5 = q[5120]; wn6 = q[6144]; wn7 = q[7168];
            } else {
                wn0 = wc0; wn1 = wc1; wn2 = wc2; wn3 = wc3;
                wn4 = wc4; wn5 = wc5; wn6 = wc6; wn7 = wc7;
            }
            unsigned m0 = (unsigned)__builtin_amdgcn_readfirstlane((int)s2m[i0 + 0]);
            unsigned m1 = (unsigned)__builtin_amdgcn_readfirstlane((int)s2m[i0 + 1]);
            unsigned m2 = (unsigned)__builtin_amdgcn_readfirstlane((int)s2m[i0 + 2]);
            unsigned m3 = (unsigned)__builtin_amdgcn_readfirstlane((int)s2m[i0 + 3]);
            unsigned m4 = (unsigned)__builtin_amdgcn_readfirstlane((int)s2m[i0 + 4]);
            unsigned m5 = (unsigned)__builtin_amdgcn_readfirstlane((int)s2m[i0 + 5]);
            unsigned m6 = (unsigned)__builtin_amdgcn_readfirstlane((int)s2m[i0 + 6]);
            unsigned m7 = (unsigned)__builtin_amdgcn_readfirstlane((int)s2m[i0 + 7]);
            double dw;
            dw = (double)wc0; FMA32(m0, dw);
            dw = (double)wc1; FMA32(m1, dw);
            dw = (double)wc2; FMA32(m2, dw);
            dw = (double)wc3; FMA32(m3, dw);
            dw = (double)wc4; FMA32(m4, dw);
            dw = (double)wc5; FMA32(m5, dw);
            dw = (double)wc6; FMA32(m6, dw);
            dw = (double)wc7; FMA32(m7, dw);
            wc0 = wn0; wc1 = wn1; wc2 = wn2; wc3 = wn3;
            wc4 = wn4; wc5 = wn5; wc6 = wn6; wc7 = wn7;
        }
    }

    h1g[(size_t)(b0 + 0)  * 1024 + n] = a0;
    h1g[(size_t)(b0 + 1)  * 1024 + n] = a1;
    h1g[(size_t)(b0 + 2)  * 1024 + n] = a2;
    h1g[(size_t)(b0 + 3)  * 1024 + n] = a3;
    h1g[(size_t)(b0 + 4)  * 1024 + n] = a4;
    h1g[(size_t)(b0 + 5)  * 1024 + n] = a5;
    h1g[(size_t)(b0 + 6)  * 1024 + n] = a6;
    h1g[(size_t)(b0 + 7)  * 1024 + n] = a7;
    h1g[(size_t)(b0 + 8)  * 1024 + n] = a8;
    h1g[(size_t)(b0 + 9)  * 1024 + n] = a9;
    h1g[(size_t)(b0 + 10) * 1024 + n] = a10;
    h1g[(size_t)(b0 + 11) * 1024 + n] = a11;
    h1g[(size_t)(b0 + 12) * 1024 + n] = a12;
    h1g[(size_t)(b0 + 13) * 1024 + n] = a13;
    h1g[(size_t)(b0 + 14) * 1024 + n] = a14;
    h1g[(size_t)(b0 + 15) * 1024 + n] = a15;
    h1g[(size_t)(b0 + 16) * 1024 + n] = a16;
    h1g[(size_t)(b0 + 17) * 1024 + n] = a17;
    h1g[(size_t)(b0 + 18) * 1024 + n] = a18;
    h1g[(size_t)(b0 + 19) * 1024 + n] = a19;
    h1g[(size_t)(b0 + 20) * 1024 + n] = a20;
    h1g[(size_t)(b0 + 21) * 1024 + n] = a21;
    h1g[(size_t)(b0 + 22) * 1024 + n] = a22;
    h1g[(size_t)(b0 + 23) * 1024 + n] = a23;
    h1g[(size_t)(b0 + 24) * 1024 + n] = a24;
    h1g[(size_t)(b0 + 25) * 1024 + n] = a25;
    h1g[(size_t)(b0 + 26) * 1024 + n] = a26;
    h1g[(size_t)(b0 + 27) * 1024 + n] = a27;
    h1g[(size_t)(b0 + 28) * 1024 + n] = a28;
    h1g[(size_t)(b0 + 29) * 1024 + n] = a29;
    h1g[(size_t)(b0 + 30) * 1024 + n] = a30;
    h1g[(size_t)(b0 + 31) * 1024 + n] = a31;
}

// h2[b,nn] = b2[nn] + sum_h s1[b,h] W2Tf[h,nn]
__global__ __launch_bounds__(256) void init_h2(
    const float* __restrict__ s1i, const float* __restrict__ W2Tf,
    const float* __restrict__ b2, double* __restrict__ h2g)
{
    const int tid = threadIdx.x;
    const int ug  = blockIdx.x & 1;          // unit group (2 x 256)
    const int b0  = (blockIdx.x >> 1) << 4;  // row group base (16 rows)
    const int nn  = (ug << 8) + tid;

    __shared__ unsigned short s1m[1024];

    for (int i = tid; i < 1024; i += 256) {
        unsigned m = 0;
        #pragma unroll
        for (int bb = 0; bb < 16; ++bb)
            m |= (s1i[(size_t)(b0 + bb) * 1024 + i] != 0.0f) ? (1u << bb) : 0u;
        s1m[i] = (unsigned short)m;
    }
    __syncthreads();

    double a0, a1, a2, a3, a4, a5, a6, a7, a8, a9, a10, a11, a12, a13, a14, a15;
    {
        double bv = (double)b2[nn];
        a0 = bv; a1 = bv; a2 = bv; a3 = bv; a4 = bv; a5 = bv; a6 = bv; a7 = bv;
        a8 = bv; a9 = bv; a10 = bv; a11 = bv; a12 = bv; a13 = bv; a14 = bv; a15 = bv;
    }

    {
        float wc0, wc1, wc2, wc3, wc4, wc5, wc6, wc7;
        {
            const float* q = W2Tf + nn;
            wc0 = q[0];    wc1 = q[512];  wc2 = q[1024]; wc3 = q[1536];
            wc4 = q[2048]; wc5 = q[2560]; wc6 = q[3072]; wc7 = q[3584];
        }
        for (int i0 = 0; i0 < 1024; i0 += 8) {
            float wn0, wn1, wn2, wn3, wn4, wn5, wn6, wn7;
            if (i0 + 8 < 1024) {
                const float* q = W2Tf + (size_t)(i0 + 8) * 512 + nn;
                wn0 = q[0];    wn1 = q[512];  wn2 = q[1024]; wn3 = q[1536];
                wn4 = q[2048]; wn5 = q[2560]; wn6 = q[3072]; wn7 = q[3584];
            } else {
                wn0 = wc0; wn1 = wc1; wn2 = wc2; wn3 = wc3;
                wn4 = wc4; wn5 = wc5; wn6 = wc6; wn7 = wc7;
            }
            unsigned m0 = (unsigned)__builtin_amdgcn_readfirstlane((int)s1m[i0 + 0]);
            unsigned m1 = (unsigned)__builtin_amdgcn_readfirstlane((int)s1m[i0 + 1]);
            unsigned m2 = (unsigned)__builtin_amdgcn_readfirstlane((int)s1m[i0 + 2]);
            unsigned m3 = (unsigned)__builtin_amdgcn_readfirstlane((int)s1m[i0 + 3]);
            unsigned m4 = (unsigned)__builtin_amdgcn_readfirstlane((int)s1m[i0 + 4]);
            unsigned m5 = (unsigned)__builtin_amdgcn_readfirstlane((int)s1m[i0 + 5]);
            unsigned m6 = (unsigned)__builtin_amdgcn_readfirstlane((int)s1m[i0 + 6]);
            unsigned m7 = (unsigned)__builtin_amdgcn_readfirstlane((int)s1m[i0 + 7]);
            double dw;
            dw = (double)wc0; FMA16(m0, dw);
            dw = (double)wc1; FMA16(m1, dw);
            dw = (double)wc2; FMA16(m2, dw);
            dw = (double)wc3; FMA16(m3, dw);
            dw = (double)wc4; FMA16(m4, dw);
            dw = (double)wc5; FMA16(m5, dw);
            dw = (double)wc6; FMA16(m6, dw);
            dw = (double)wc7; FMA16(m7, dw);
            wc0 = wn0; wc1 = wn1; wc2 = wn2; wc3 = wn3;
            wc4 = wn4; wc5 = wn5; wc6 = wn6; wc7 = wn7;
        }
    }

    h2g[(size_t)(b0 + 0)  * 512 + nn] = a0;
    h2g[(size_t)(b0 + 1)  * 512 + nn] = a1;
    h2g[(size_t)(b0 + 2)  * 512 + nn] = a2;
    h2g[(size_t)(b0 + 3)  * 512 + nn] = a3;
    h2g[(size_t)(b0 + 4)  * 512 + nn] = a4;
    h2g[(size_t)(b0 + 5)  * 512 + nn] = a5;
    h2g[(size_t)(b0 + 6)  * 512 + nn] = a6;
    h2g[(size_t)(b0 + 7)  * 512 + nn] = a7;
    h2g[(size_t)(b0 + 8)  * 512 + nn] = a8;
    h2g[(size_t)(b0 + 9)  * 512 + nn] = a9;
    h2g[(size_t)(b0 + 10) * 512 + nn] = a10;
    h2g[(size_t)(b0 + 11) * 512 + nn] = a11;
    h2g[(size_t)(b0 + 12) * 512 + nn] = a12;
    h2g[(size_t)(b0 + 13) * 512 + nn] = a13;
    h2g[(size_t)(b0 + 14) * 512 + nn] = a14;
    h2g[(size_t)(b0 + 15) * 512 + nn] = a15;
}

// ---------------- Gibbs chain: TWO batch rows per wave -----------------------
// Rows bA=2*blk, bB=2*blk+1 share: the wx burst (one copy), and the coupling-
// row gathers (loaded once for the UNION of both rows' flips; applied to each
// row's fields only where that row flipped -- wave-uniform scalar branches).
// Per-row FMA sequences remain ascending-j with identical values ->
// bit-identical to the single-row kernel. Traffic: -25% gathers, -50% wx.

#define LOADQ(NC, Q0, Q1, Q2, Q3) { \
    if ((NC) < N_H) { \
        const float4* p_ = (const float4*)(WHf + ((size_t)(NC) << 9) + (lane << 3)); \
        Q0 = p_[0]; Q1 = p_[1]; Q2 = Q1; Q3 = Q1; \
    } else { \
        const float4* p_ = (const float4*)(WOf + ((size_t)((NC) - N_H) << 10) + (lane << 4)); \
        Q0 = p_[0]; Q1 = p_[1]; Q2 = p_[2]; Q3 = p_[3]; \
    } }

// Apply one flip to row R's fields (H1/H2 arrays, AV = that row's decision bits)
#define APPLYF(H1, H2, AV, JC, NC, Q0, Q1, Q2, Q3) { \
    const double sd = (((AV) >> (JC)) & 1ull) ? 1.0 : -1.0; \
    if ((NC) < N_H) { \
        H2[0] = fma(sd, (double)Q0.x, H2[0]); \
        H2[1] = fma(sd, (double)Q0.y, H2[1]); \
        H2[2] = fma(sd, (double)Q0.z, H2[2]); \
        H2[3] = fma(sd, (double)Q0.w, H2[3]); \
        H2[4] = fma(sd, (double)Q1.x, H2[4]); \
        H2[5] = fma(sd, (double)Q1.y, H2[5]); \
        H2[6] = fma(sd, (double)Q1.z, H2[6]); \
        H2[7] = fma(sd, (double)Q1.w, H2[7]); \
    } else { \
        H1[0]  = fma(sd, (double)Q0.x, H1[0]); \
        H1[1]  = fma(sd, (double)Q0.y, H1[1]); \
        H1[2]  = fma(sd, (double)Q0.z, H1[2]); \
        H1[3]  = fma(sd, (double)Q0.w, H1[3]); \
        H1[4]  = fma(sd, (double)Q1.x, H1[4]); \
        H1[5]  = fma(sd, (double)Q1.y, H1[5]); \
        H1[6]  = fma(sd, (double)Q1.z, H1[6]); \
        H1[7]  = fma(sd, (double)Q1.w, H1[7]); \
        H1[8]  = fma(sd, (double)Q2.x, H1[8]); \
        H1[9]  = fma(sd, (double)Q2.y, H1[9]); \
        H1[10] = fma(sd, (double)Q2.z, H1[10]); \
        H1[11] = fma(sd, (double)Q2.w, H1[11]); \
        H1[12] = fma(sd, (double)Q3.x, H1[12]); \
        H1[13] = fma(sd, (double)Q3.y, H1[13]); \
        H1[14] = fma(sd, (double)Q3.z, H1[14]); \
        H1[15] = fma(sd, (double)Q3.w, H1[15]); \
    } }

// Apply unit (J,N) with fragments Q: to row A if CA bit set, row B if CB bit set
#define APPLY2(J, N, Q0, Q1, Q2, Q3) { \
    if ((CA >> (J)) & 1ull) APPLYF(h1A, h2A, AA, J, N, Q0, Q1, Q2, Q3); \
    if ((CB >> (J)) & 1ull) APPLYF(h1B, h2B, AB, J, N, Q0, Q1, Q2, Q3); }

__global__ __launch_bounds__(64, 2) void gibbs(
    const double* __restrict__ thT, const int* __restrict__ ids,
    const float* __restrict__ WHf, const float* __restrict__ WOf,
    const float* __restrict__ WXf,
    const int* __restrict__ pos2, const int* __restrict__ posB,
    const double* __restrict__ h1g, const double* __restrict__ h2g,
    const float* __restrict__ s1i, const float* __restrict__ s2i,
    float* __restrict__ out)
{
    const int lane = threadIdx.x;          // 0..63
    const int bA = blockIdx.x * 2;         // batch rows
    const int bB = bA + 1;

    __shared__ double fldA[1536], fldB[1536];          // field mirrors
    __shared__ unsigned long long actA[N_WIN], actB[N_WIN];
    __shared__ unsigned long long sbA[24], sbB[24];

    // both rows' master fields in registers (nontemporal: read-once)
    double h1A[16], h2A[8], h1B[16], h2B[8];
    #pragma unroll
    for (int k = 0; k < 16; ++k) {
        h1A[k] = __builtin_nontemporal_load(&h1g[(size_t)bA * 1024 + k * 64 + lane]);
        h1B[k] = __builtin_nontemporal_load(&h1g[(size_t)bB * 1024 + k * 64 + lane]);
    }
    #pragma unroll
    for (int k = 0; k < 8; ++k) {
        h2A[k] = __builtin_nontemporal_load(&h2g[(size_t)bA * 512 + k * 64 + lane]);
        h2B[k] = __builtin_nontemporal_load(&h2g[(size_t)bB * 512 + k * 64 + lane]);
    }

    // initial-state bitmasks for both rows
    #pragma unroll
    for (int k = 0; k < 16; ++k) {
        float vA = __builtin_nontemporal_load(&s1i[(size_t)bA * 1024 + k * 64 + lane]);
        float vB = __builtin_nontemporal_load(&s1i[(size_t)bB * 1024 + k * 64 + lane]);
        unsigned long long mA = __ballot(vA != 0.0f);
        unsigned long long mB = __ballot(vB != 0.0f);
        if (lane == 0) { sbA[k] = mA; sbB[k] = mB; }
    }
    #pragma unroll
    for (int k = 0; k < 8; ++k) {
        float vA = __builtin_nontemporal_load(&s2i[(size_t)bA * 512 + k * 64 + lane]);
        float vB = __builtin_nontemporal_load(&s2i[(size_t)bB * 512 + k * 64 + lane]);
        unsigned long long mA = __ballot(vA != 0.0f);
        unsigned long long mB = __ballot(vB != 0.0f);
        if (lane == 0) { sbA[16 + k] = mA; sbB[16 + k] = mB; }
    }

    // window-0 setup
    int idw = ids[lane];
    double thcA = __builtin_nontemporal_load(&thT[(size_t)bA * 3072 + lane]);
    double thcB = __builtin_nontemporal_load(&thT[(size_t)bB * 3072 + lane]);
    int p2c = 0;

    for (int w = 0; w < N_WIN; ++w) {
        const int t0 = w * 64;

        // wx burst: ONE copy serves both rows
        const float* wxp = WXf + ((size_t)w << 12) + lane;
        float wx32[64];
        #pragma unroll
        for (int j = 0; j < 64; ++j) wx32[j] = wxp[(size_t)j * 64];

        // next-window loads
        int idn = 0; double thnA = 0.0, thnB = 0.0; int p2n = 0;
        if (w + 1 < N_WIN) {
            idn = ids[t0 + 64 + lane];
            thnA = __builtin_nontemporal_load(&thT[(size_t)bA * 3072 + t0 + 64 + lane]);
            thnB = __builtin_nontemporal_load(&thT[(size_t)bB * 3072 + t0 + 64 + lane]);
            if (w + 1 >= 24) p2n = pos2[(w + 1 - 24) * 64 + lane];
        }

        // old states
        int oldA, oldB;
        if (w < 24) {
            unsigned long long svA = sbA[idw >> 6];
            unsigned long long svB = sbB[idw >> 6];
            oldA = (int)((svA >> (idw & 63)) & 1ull);
            oldB = (int)((svB >> (idw & 63)) & 1ull);
        } else {
            unsigned long long avA = actA[p2c >> 6];
            unsigned long long avB = actB[p2c >> 6];
            oldA = (int)((avA >> (p2c & 63)) & 1ull);
            oldB = (int)((avB >> (p2c & 63)) & 1ull);
        }
        unsigned long long OLDA = __ballot(oldA != 0);
        unsigned long long OLDB = __ballot(oldB != 0);

        // mirror fields, gather decision scalars
        #pragma unroll
        for (int k = 0; k < 16; ++k) { fldA[k * 64 + lane] = h1A[k]; fldB[k * 64 + lane] = h1B[k]; }
        #pragma unroll
        for (int k = 0; k < 8; ++k)  { fldA[1024 + k * 64 + lane] = h2A[k]; fldB[1024 + k * 64 + lane] = h2B[k]; }
        double gA = fldA[idw];
        double gB = fldB[idw];

        // twin decision chains (independent -> interleave on the serial latency)
        unsigned long long AA = 0, AB = 0;
        #pragma unroll
        for (int j = 0; j < 64; ++j) {
            unsigned long long balA = __ballot(gA > thcA);
            unsigned long long balB = __ballot(gB > thcB);
            unsigned long long aA = (balA >> j) & 1ull;
            unsigned long long aB = (balB >> j) & 1ull;
            AA |= aA << j;
            AB |= aB << j;
            unsigned long long oA = (OLDA >> j) & 1ull;
            unsigned long long oB = (OLDB >> j) & 1ull;
            unsigned long long duA = aA ? (oA ? 0ull : 0x3FF0000000000000ull)
                                        : (oA ? 0xBFF0000000000000ull : 0ull);
            unsigned long long duB = aB ? (oB ? 0ull : 0x3FF0000000000000ull)
                                        : (oB ? 0xBFF0000000000000ull : 0ull);
            double wd = (double)wx32[j];
            gA = fma(__builtin_bit_cast(double, duA), wd, gA);
            gB = fma(__builtin_bit_cast(double, duB), wd, gB);
        }
        if (lane == 0) { actA[w] = AA; actB[w] = AB; }

        // apply phase: union of both rows' flips, each row loaded ONCE;
        // ascending-j order preserved per row (bit-identical). Last window skipped.
        if (w + 1 < N_WIN) {
            unsigned long long CA = AA ^ OLDA;
            unsigned long long CB = AB ^ OLDB;
            unsigned long long CU = CA | CB;
            while (CU) {
                int j0 = __builtin_ctzll(CU); CU &= CU - 1;
                int n0 = __builtin_amdgcn_readlane(idw, j0);
                int j1 = 0, n1 = 0, j2 = 0, n2 = 0, j3 = 0, n3 = 0;
                int cnt = 1;
                if (CU) {
                    j1 = __builtin_ctzll(CU); CU &= CU - 1;
                    n1 = __builtin_amdgcn_readlane(idw, j1); cnt = 2;
                    if (CU) {
                        j2 = __builtin_ctzll(CU); CU &= CU - 1;
                        n2 = __builtin_amdgcn_readlane(idw, j2); cnt = 3;
                        if (CU) {
                            j3 = __builtin_ctzll(CU); CU &= CU - 1;
                            n3 = __builtin_amdgcn_readlane(idw, j3); cnt = 4;
                        }
                    }
                }
                float4 a0, a1, a2, a3, b0, b1, b2, b3;
                float4 c0, c1, c2, c3, d0, d1, d2, d3;
                LOADQ(n0, a0, a1, a2, a3);
                if (cnt > 1) LOADQ(n1, b0, b1, b2, b3);
                if (cnt > 2) LOADQ(n2, c0, c1, c2, c3);
                if (cnt > 3) LOADQ(n3, d0, d1, d2, d3);
                APPLY2(j0, n0, a0, a1, a2, a3);
                if (cnt > 1) APPLY2(j1, n1, b0, b1, b2, b3);
                if (cnt > 2) APPLY2(j2, n2, c0, c1, c2, c3);
                if (cnt > 3) APPLY2(j3, n3, d0, d1, d2, d3);
            }
        }

        idw = idn; thcA = thnA; thcB = thnB; p2c = p2n;
    }

    // epilogue: both rows' final states from sweep-2 decision bits
    #pragma unroll
    for (int k = 0; k < 16; ++k) {
        int p = posB[k * 64 + lane];
        unsigned long long avA = actA[24 + (p >> 6)];
        unsigned long long avB = actB[24 + (p >> 6)];
        __builtin_nontemporal_store((float)((avA >> (p & 63)) & 1ull),
                                    &out[(size_t)bA * 2560 + 1024 + k * 64 + lane]);
        __builtin_nontemporal_store((float)((avB >> (p & 63)) & 1ull),
                                    &out[(size_t)bB * 2560 + 1024 + k * 64 + lane]);
    }
    #pragma unroll
    for (int k = 0; k < 8; ++k) {
        int p = posB[1024 + k * 64 + lane];
        unsigned long long avA = actA[24 + (p >> 6)];
        unsigned long long avB = actB[24 + (p >> 6)];
        __builtin_nontemporal_store((float)((avA >> (p & 63)) & 1ull),
                                    &out[(size_t)bA * 2560 + 2048 + k * 64 + lane]);
        __builtin_nontemporal_store((float)((avB >> (p & 63)) & 1ull),
                                    &out[(size_t)bB * 2560 + 2048 + k * 64 + lane]);
    }
}

// ---------------- launch ----------------
extern "C" void kernel_launch(void* const* d_in, const int* in_sizes, int n_in,
                              void* d_out, int out_size, void* d_ws, size_t ws_size,
                              hipStream_t stream) {
    const float* x   = (const float*)d_in[0];
    const float* s1i = (const float*)d_in[1];
    const float* s2i = (const float*)d_in[2];
    const float* W1  = (const float*)d_in[3];
    const float* b1  = (const float*)d_in[4];
    const float* W2  = (const float*)d_in[5];
    const float* b2  = (const float*)d_in[6];
    const float* u   = (const float*)d_in[7];
    const int*   ids = (const int*)d_in[8];
    float* out = (float*)d_out;

    char* ws = (char*)d_ws;
    float*  W1T  = (float*) (ws);                               //  4 MB
    float*  W2Tf = (float*) (ws + ((size_t)4  << 20));          //  2 MB
    float*  WHf  = (float*) (ws + ((size_t)6  << 20));          //  2 MB
    float*  WOf  = (float*) (ws + ((size_t)8  << 20));          //  2 MB
    float*  WXf  = (float*) (ws + ((size_t)10 << 20));          //  768 KB
    int*    posA = (int*)   (ws + ((size_t)11 << 20));          //  6 KB
    int*    posB = (int*)   (ws + ((size_t)11 << 20) + 8192);   //  6 KB
    int*    pos2 = (int*)   (ws + ((size_t)11 << 20) + 16384);  //  6 KB
    double* thT  = (double*)(ws + ((size_t)12 << 20));          // 48 MB
    double* h1g  = (double*)(ws + ((size_t)60 << 20));          // 16 MB
    double* h2g  = (double*)(ws + ((size_t)76 << 20));          //  8 MB (total 84 MB)

    hipLaunchKernelGGL(prep_w1t,  dim3(4096), dim3(256), 0, stream, W1, W1T);
    hipLaunchKernelGGL(prep_w2tf, dim3(2048), dim3(256), 0, stream, W2, W2Tf);
    hipLaunchKernelGGL(prep_whf,  dim3(2048), dim3(256), 0, stream, W2, WHf);
    hipLaunchKernelGGL(prep_wof,  dim3(2048), dim3(256), 0, stream, W2, WOf);
    hipLaunchKernelGGL(prep_wx,   dim3(768),  dim3(256), 0, stream, W2, ids, WXf);
    hipLaunchKernelGGL(prep_pos,  dim3(12),   dim3(256), 0, stream, ids, posA, posB);
    hipLaunchKernelGGL(prep_pos2, dim3(6),    dim3(256), 0, stream, ids, posA, pos2);
    hipLaunchKernelGGL(prep_th,   dim3(1536), dim3(256), 0, stream, u, thT);
    hipLaunchKernelGGL(copy_x,    dim3(2048), dim3(256), 0, stream, x, out);
    hipLaunchKernelGGL(init_h1,   dim3(256),  dim3(256), 0, stream,
                       x, s2i, W1T, W2, b1, h1g);
    hipLaunchKernelGGL(init_h2,   dim3(256),  dim3(256), 0, stream,
                       s1i, W2Tf, b2, h2g);
    hipLaunchKernelGGL(gibbs, dim3(1024), dim3(64), 0, stream,
                       thT, ids, WHf, WOf, WXf, pos2, posB, h1g, h2g, s1i, s2i, out);
}

// Round 10
// 1158.738 us; speedup vs baseline: 1.5290x; 1.5290x over previous
//
#include <hip/hip_runtime.h>
#include <math.h>

// Problem constants
#define B_TOT   2048
#define N_IN    1024
#define N_H     1024
#define N_OUT   512
#define N_UPD   1536
#define T_TOT   3072   // MAX_STEPS * N_UPD
#define N_WIN   48     // T_TOT / 64

// ---------------- prep kernels ----------------

// W1T[c*1024 + r] = W1[r*1024 + c]   (LDS-tiled, coalesced both sides)
__global__ __launch_bounds__(256) void prep_w1t(const float* __restrict__ W1,
                                                float* __restrict__ W1T) {
    __shared__ float tile[64][65];
    int tc = blockIdx.x & 15;     // c tile (16)
    int tr = blockIdx.x >> 4;     // r tile (16)
    int tx = threadIdx.x & 63;
    int ty0 = threadIdx.x >> 6;   // 0..3
    for (int rr = ty0; rr < 64; rr += 4)
        tile[rr][tx] = W1[(size_t)(tr * 64 + rr) * 1024 + tc * 64 + tx];
    __syncthreads();
    for (int rr = ty0; rr < 64; rr += 4)
        W1T[(size_t)(tc * 64 + rr) * 1024 + tr * 64 + tx] = tile[tx][rr];
}

// W2Tf[c*512 + r] = W2[r*1024 + c]   (LDS-tiled)
__global__ __launch_bounds__(256) void prep_w2tf(const float* __restrict__ W2,
                                                 float* __restrict__ W2Tf) {
    __shared__ float tile[64][65];
    int tc = blockIdx.x & 15;     // c tile over 1024 (16)
    int tr = blockIdx.x >> 4;     // r tile over 512  (8)
    int tx = threadIdx.x & 63;
    int ty0 = threadIdx.x >> 6;
    for (int rr = ty0; rr < 64; rr += 4)
        tile[rr][tx] = W2[(size_t)(tr * 64 + rr) * 1024 + tc * 64 + tx];
    __syncthreads();
    for (int rr = ty0; rr < 64; rr += 4)
        W2Tf[(size_t)(tc * 64 + rr) * 512 + tr * 64 + tx] = tile[tx][rr];
}

// WHf[n][lane][j] = W2[(j*64+l)][n]   (hidden-flip fragment, fp32, j fast 0..7)
__global__ void prep_whf(const float* __restrict__ W2, float* __restrict__ WHf) {
    int idx = blockIdx.x * 256 + threadIdx.x;   // < 1024*512
    int n = idx >> 9;
    int r = idx & 511;
    int l = r >> 3, j = r & 7;
    WHf[idx] = W2[(size_t)(j * 64 + l) * 1024 + n];
}

// WOf[nn][lane][j] = W2[nn][j*64+lane]   (output-flip fragment, fp32, j fast 0..15)
__global__ void prep_wof(const float* __restrict__ W2, float* __restrict__ WOf) {
    int idx = blockIdx.x * 256 + threadIdx.x;   // < 512*1024
    int nn = idx >> 10;
    int r = idx & 1023;
    int l = r >> 4, j = r & 15;
    WOf[idx] = W2[(size_t)nn * 1024 + j * 64 + l];
}

// WXf[w][j][l]: fp32 coupling of flip at step w*64+j onto decision at step w*64+l.
__global__ void prep_wx(const float* __restrict__ W2, const int* __restrict__ ids,
                        float* __restrict__ WXf) {
    int idx = blockIdx.x * 256 + threadIdx.x;   // < 48*4096
    int w = idx >> 12;
    int j = (idx >> 6) & 63;
    int l = idx & 63;
    int mj = ids[w * 64 + j];
    int nl = ids[w * 64 + l];
    float v = 0.0f;
    if (mj < N_H && nl >= N_H) v = W2[(size_t)(nl - N_H) * 1024 + mj];
    else if (mj >= N_H && nl < N_H) v = W2[(size_t)(mj - N_H) * 1024 + nl];
    WXf[idx] = v;
}

// posA[n] = sweep-1 step of unit n; posB[n] = sweep-2 step - 1536
__global__ void prep_pos(const int* __restrict__ ids, int* __restrict__ posA,
                         int* __restrict__ posB) {
    int t = blockIdx.x * 256 + threadIdx.x;   // < 3072
    int n = ids[t];
    if (t < N_UPD) posA[n] = t; else posB[n] = t - N_UPD;
}

// pos2[t] = posA[ids[1536 + t]]  (coalesced sweep-2 old-state locator)
__global__ void prep_pos2(const int* __restrict__ ids, const int* __restrict__ posA,
                          int* __restrict__ pos2) {
    int t = blockIdx.x * 256 + threadIdx.x;   // < 1536
    pos2[t] = posA[ids[N_UPD + t]];
}

// thT[b][t] = T(t) * (log(u[t][b]) - log1p(-u[t][b]))  in f64 — EXACT same
// expression/order as the previously-passing in-gibbs computation.
__global__ __launch_bounds__(256) void prep_th(const float* __restrict__ u,
                                               double* __restrict__ thT) {
    __shared__ double tile[64][65];
    int bt = blockIdx.x % 48;     // t tile
    int bb = blockIdx.x / 48;     // b tile
    int tx = threadIdx.x & 63;
    int ty0 = threadIdx.x >> 6;   // 0..3
    const double T1c = (double)(float)(2.0 / exp((double)1 / 5.0));
    for (int r = ty0; r < 64; r += 4) {
        int t = bt * 64 + r;
        double ud = (double)u[(size_t)t * 2048 + bb * 64 + tx];
        double T = (t >= N_UPD) ? T1c : 2.0;
        tile[r][tx] = T * (log(ud) - log1p(-ud));
    }
    __syncthreads();
    for (int r = ty0; r < 64; r += 4)
        thT[(size_t)(bb * 64 + r) * 3072 + bt * 64 + tx] = tile[tx][r];
}

// out[b][0:1024] = x[b][:]
__global__ void copy_x(const float* __restrict__ x, float* __restrict__ out) {
    int idx = blockIdx.x * 256 + threadIdx.x;   // < 2048*256 (float4 units)
    int b = idx >> 8, c = idx & 255;
    ((float4*)(out + (size_t)b * 2560))[c] = ((const float4*)(x + (size_t)b * 1024))[c];
}

// ---------------- init fields (fp64) ----------------------------------------
// Branch-free accumulate: acc_r = fma(bit?1.0:0.0, dw, acc_r) — bit-identical
// (fma(0,dw,a)==a; fma(1,dw,a)==a+dw, same ascending-input order).
// 512 blocks each (2 blocks/CU = 2 waves/SIMD) so weight-load latency is
// hidden; weights stay L2-shared across the co-resident blocks.

#define FMA16(M, DW) { \
    a0  = fma(((M) & 0x0001u) ? 1.0 : 0.0, (DW), a0 ); \
    a1  = fma(((M) & 0x0002u) ? 1.0 : 0.0, (DW), a1 ); \
    a2  = fma(((M) & 0x0004u) ? 1.0 : 0.0, (DW), a2 ); \
    a3  = fma(((M) & 0x0008u) ? 1.0 : 0.0, (DW), a3 ); \
    a4  = fma(((M) & 0x0010u) ? 1.0 : 0.0, (DW), a4 ); \
    a5  = fma(((M) & 0x0020u) ? 1.0 : 0.0, (DW), a5 ); \
    a6  = fma(((M) & 0x0040u) ? 1.0 : 0.0, (DW), a6 ); \
    a7  = fma(((M) & 0x0080u) ? 1.0 : 0.0, (DW), a7 ); \
    a8  = fma(((M) & 0x0100u) ? 1.0 : 0.0, (DW), a8 ); \
    a9  = fma(((M) & 0x0200u) ? 1.0 : 0.0, (DW), a9 ); \
    a10 = fma(((M) & 0x0400u) ? 1.0 : 0.0, (DW), a10); \
    a11 = fma(((M) & 0x0800u) ? 1.0 : 0.0, (DW), a11); \
    a12 = fma(((M) & 0x1000u) ? 1.0 : 0.0, (DW), a12); \
    a13 = fma(((M) & 0x2000u) ? 1.0 : 0.0, (DW), a13); \
    a14 = fma(((M) & 0x4000u) ? 1.0 : 0.0, (DW), a14); \
    a15 = fma(((M) & 0x8000u) ? 1.0 : 0.0, (DW), a15); }

#define FMA8(M, DW) { \
    a0 = fma(((M) & 0x01u) ? 1.0 : 0.0, (DW), a0); \
    a1 = fma(((M) & 0x02u) ? 1.0 : 0.0, (DW), a1); \
    a2 = fma(((M) & 0x04u) ? 1.0 : 0.0, (DW), a2); \
    a3 = fma(((M) & 0x08u) ? 1.0 : 0.0, (DW), a3); \
    a4 = fma(((M) & 0x10u) ? 1.0 : 0.0, (DW), a4); \
    a5 = fma(((M) & 0x20u) ? 1.0 : 0.0, (DW), a5); \
    a6 = fma(((M) & 0x40u) ? 1.0 : 0.0, (DW), a6); \
    a7 = fma(((M) & 0x80u) ? 1.0 : 0.0, (DW), a7); }

// h1[b,n] = b1[n] + sum_i x[b,i] W1T[i,n] + sum_o s2[b,o] W2[o,n]
// 16 rows per block; grid = (2048/16) * 4 unit groups = 512 blocks.
__global__ __launch_bounds__(256) void init_h1(
    const float* __restrict__ x, const float* __restrict__ s2i,
    const float* __restrict__ W1T, const float* __restrict__ W2,
    const float* __restrict__ b1, double* __restrict__ h1g)
{
    const int tid = threadIdx.x;
    const int ug  = blockIdx.x & 3;          // unit group (4 x 256)
    const int b0  = (blockIdx.x >> 2) << 4;  // row group base (16 rows)
    const int n   = (ug << 8) + tid;

    __shared__ unsigned short xm[1024];
    __shared__ unsigned short s2m[512];

    for (int i = tid; i < 1024; i += 256) {
        unsigned m = 0;
        #pragma unroll
        for (int bb = 0; bb < 16; ++bb)
            m |= (x[(size_t)(b0 + bb) * 1024 + i] != 0.0f) ? (1u << bb) : 0u;
        xm[i] = (unsigned short)m;
    }
    for (int j = tid; j < 512; j += 256) {
        unsigned m = 0;
        #pragma unroll
        for (int bb = 0; bb < 16; ++bb)
            m |= (s2i[(size_t)(b0 + bb) * 512 + j] != 0.0f) ? (1u << bb) : 0u;
        s2m[j] = (unsigned short)m;
    }
    __syncthreads();

    double a0, a1, a2, a3, a4, a5, a6, a7, a8, a9, a10, a11, a12, a13, a14, a15;
    {
        double bv = (double)b1[n];
        a0 = bv; a1 = bv; a2 = bv; a3 = bv; a4 = bv; a5 = bv; a6 = bv; a7 = bv;
        a8 = bv; a9 = bv; a10 = bv; a11 = bv; a12 = bv; a13 = bv; a14 = bv; a15 = bv;
    }

    // part 1: x @ W1^T, i ascending (1-group-deep weight prefetch)
    {
        float wc0, wc1, wc2, wc3, wc4, wc5, wc6, wc7;
        {
            const float* q = W1T + n;
            wc0 = q[0];    wc1 = q[1024]; wc2 = q[2048]; wc3 = q[3072];
            wc4 = q[4096]; wc5 = q[5120]; wc6 = q[6144]; wc7 = q[7168];
        }
        for (int i0 = 0; i0 < 1024; i0 += 8) {
            float wn0, wn1, wn2, wn3, wn4, wn5, wn6, wn7;
            if (i0 + 8 < 1024) {
                const float* q = W1T + (size_t)(i0 + 8) * 1024 + n;
                wn0 = q[0];    wn1 = q[1024]; wn2 = q[2048]; wn3 = q[3072];
                wn4 = q[4096]; wn5 = q[5120]; wn6 = q[6144]; wn7 = q[7168];
            } else {
                wn0 = wc0; wn1 = wc1; wn2 = wc2; wn3 = wc3;
                wn4 = wc4; wn5 = wc5; wn6 = wc6; wn7 = wc7;
            }
            unsigned m0 = (unsigned)__builtin_amdgcn_readfirstlane((int)xm[i0 + 0]);
            unsigned m1 = (unsigned)__builtin_amdgcn_readfirstlane((int)xm[i0 + 1]);
            unsigned m2 = (unsigned)__builtin_amdgcn_readfirstlane((int)xm[i0 + 2]);
            unsigned m3 = (unsigned)__builtin_amdgcn_readfirstlane((int)xm[i0 + 3]);
            unsigned m4 = (unsigned)__builtin_amdgcn_readfirstlane((int)xm[i0 + 4]);
            unsigned m5 = (unsigned)__builtin_amdgcn_readfirstlane((int)xm[i0 + 5]);
            unsigned m6 = (unsigned)__builtin_amdgcn_readfirstlane((int)xm[i0 + 6]);
            unsigned m7 = (unsigned)__builtin_amdgcn_readfirstlane((int)xm[i0 + 7]);
            double dw;
            dw = (double)wc0; FMA16(m0, dw);
            dw = (double)wc1; FMA16(m1, dw);
            dw = (double)wc2; FMA16(m2, dw);
            dw = (double)wc3; FMA16(m3, dw);
            dw = (double)wc4; FMA16(m4, dw);
            dw = (double)wc5; FMA16(m5, dw);
            dw = (double)wc6; FMA16(m6, dw);
            dw = (double)wc7; FMA16(m7, dw);
            wc0 = wn0; wc1 = wn1; wc2 = wn2; wc3 = wn3;
            wc4 = wn4; wc5 = wn5; wc6 = wn6; wc7 = wn7;
        }
    }
    // part 2: s2 @ W2, o ascending
    {
        float wc0, wc1, wc2, wc3, wc4, wc5, wc6, wc7;
        {
            const float* q = W2 + n;
            wc0 = q[0];    wc1 = q[1024]; wc2 = q[2048]; wc3 = q[3072];
            wc4 = q[4096]; wc5 = q[5120]; wc6 = q[6144]; wc7 = q[7168];
        }
        for (int i0 = 0; i0 < 512; i0 += 8) {
            float wn0, wn1, wn2, wn3, wn4, wn5, wn6, wn7;
            if (i0 + 8 < 512) {
                const float* q = W2 + (size_t)(i0 + 8) * 1024 + n;
                wn0 = q[0];    wn1 = q[1024]; wn2 = q[2048]; wn3 = q[3072];
                wn4 = q[4096]; wn5 = q[5120]; wn6 = q[6144]; wn7 = q[7168];
            } else {
                wn0 = wc0; wn1 = wc1; wn2 = wc2; wn3 = wc3;
                wn4 = wc4; wn5 = wc5; wn6 = wc6; wn7 = wc7;
            }
            unsigned m0 = (unsigned)__builtin_amdgcn_readfirstlane((int)s2m[i0 + 0]);
            unsigned m1 = (unsigned)__builtin_amdgcn_readfirstlane((int)s2m[i0 + 1]);
            unsigned m2 = (unsigned)__builtin_amdgcn_readfirstlane((int)s2m[i0 + 2]);
            unsigned m3 = (unsigned)__builtin_amdgcn_readfirstlane((int)s2m[i0 + 3]);
            unsigned m4 = (unsigned)__builtin_amdgcn_readfirstlane((int)s2m[i0 + 4]);
            unsigned m5 = (unsigned)__builtin_amdgcn_readfirstlane((int)s2m[i0 + 5]);
            unsigned m6 = (unsigned)__builtin_amdgcn_readfirstlane((int)s2m[i0 + 6]);
            unsigned m7 = (unsigned)__builtin_amdgcn_readfirstlane((int)s2m[i0 + 7]);
            double dw;
            dw = (double)wc0; FMA16(m0, dw);
            dw = (double)wc1; FMA16(m1, dw);
            dw = (double)wc2; FMA16(m2, dw);
            dw = (double)wc3; FMA16(m3, dw);
            dw = (double)wc4; FMA16(m4, dw);
            dw = (double)wc5; FMA16(m5, dw);
            dw = (double)wc6; FMA16(m6, dw);
            dw = (double)wc7; FMA16(m7, dw);
            wc0 = wn0; wc1 = wn1; wc2 = wn2; wc3 = wn3;
            wc4 = wn4; wc5 = wn5; wc6 = wn6; wc7 = wn7;
        }
    }

    h1g[(size_t)(b0 + 0)  * 1024 + n] = a0;
    h1g[(size_t)(b0 + 1)  * 1024 + n] = a1;
    h1g[(size_t)(b0 + 2)  * 1024 + n] = a2;
    h1g[(size_t)(b0 + 3)  * 1024 + n] = a3;
    h1g[(size_t)(b0 + 4)  * 1024 + n] = a4;
    h1g[(size_t)(b0 + 5)  * 1024 + n] = a5;
    h1g[(size_t)(b0 + 6)  * 1024 + n] = a6;
    h1g[(size_t)(b0 + 7)  * 1024 + n] = a7;
    h1g[(size_t)(b0 + 8)  * 1024 + n] = a8;
    h1g[(size_t)(b0 + 9)  * 1024 + n] = a9;
    h1g[(size_t)(b0 + 10) * 1024 + n] = a10;
    h1g[(size_t)(b0 + 11) * 1024 + n] = a11;
    h1g[(size_t)(b0 + 12) * 1024 + n] = a12;
    h1g[(size_t)(b0 + 13) * 1024 + n] = a13;
    h1g[(size_t)(b0 + 14) * 1024 + n] = a14;
    h1g[(size_t)(b0 + 15) * 1024 + n] = a15;
}

// h2[b,nn] = b2[nn] + sum_h s1[b,h] W2Tf[h,nn]
// 8 rows per block; grid = (2048/8) * 2 unit groups = 512 blocks.
__global__ __launch_bounds__(256) void init_h2(
    const float* __restrict__ s1i, const float* __restrict__ W2Tf,
    const float* __restrict__ b2, double* __restrict__ h2g)
{
    const int tid = threadIdx.x;
    const int ug  = blockIdx.x & 1;          // unit group (2 x 256)
    const int b0  = (blockIdx.x >> 1) << 3;  // row group base (8 rows)
    const int nn  = (ug << 8) + tid;

    __shared__ unsigned char s1m[1024];

    for (int i = tid; i < 1024; i += 256) {
        unsigned m = 0;
        #pragma unroll
        for (int bb = 0; bb < 8; ++bb)
            m |= (s1i[(size_t)(b0 + bb) * 1024 + i] != 0.0f) ? (1u << bb) : 0u;
        s1m[i] = (unsigned char)m;
    }
    __syncthreads();

    double a0, a1, a2, a3, a4, a5, a6, a7;
    {
        double bv = (double)b2[nn];
        a0 = bv; a1 = bv; a2 = bv; a3 = bv; a4 = bv; a5 = bv; a6 = bv; a7 = bv;
    }

    {
        float wc0, wc1, wc2, wc3, wc4, wc5, wc6, wc7;
        {
            const float* q = W2Tf + nn;
            wc0 = q[0];    wc1 = q[512];  wc2 = q[1024]; wc3 = q[1536];
            wc4 = q[2048]; wc5 = q[2560]; wc6 = q[3072]; wc7 = q[3584];
        }
        for (int i0 = 0; i0 < 1024; i0 += 8) {
            float wn0, wn1, wn2, wn3, wn4, wn5, wn6, wn7;
            if (i0 + 8 < 1024) {
                const float* q = W2Tf + (size_t)(i0 + 8) * 512 + nn;
                wn0 = q[0];    wn1 = q[512];  wn2 = q[1024]; wn3 = q[1536];
                wn4 = q[2048]; wn5 = q[2560]; wn6 = q[3072]; wn7 = q[3584];
            } else {
                wn0 = wc0; wn1 = wc1; wn2 = wc2; wn3 = wc3;
                wn4 = wc4; wn5 = wc5; wn6 = wc6; wn7 = wc7;
            }
            unsigned m0 = (unsigned)__builtin_amdgcn_readfirstlane((int)s1m[i0 + 0]);
            unsigned m1 = (unsigned)__builtin_amdgcn_readfirstlane((int)s1m[i0 + 1]);
            unsigned m2 = (unsigned)__builtin_amdgcn_readfirstlane((int)s1m[i0 + 2]);
            unsigned m3 = (unsigned)__builtin_amdgcn_readfirstlane((int)s1m[i0 + 3]);
            unsigned m4 = (unsigned)__builtin_amdgcn_readfirstlane((int)s1m[i0 + 4]);
            unsigned m5 = (unsigned)__builtin_amdgcn_readfirstlane((int)s1m[i0 + 5]);
            unsigned m6 = (unsigned)__builtin_amdgcn_readfirstlane((int)s1m[i0 + 6]);
            unsigned m7 = (unsigned)__builtin_amdgcn_readfirstlane((int)s1m[i0 + 7]);
            double dw;
            dw = (double)wc0; FMA8(m0, dw);
            dw = (double)wc1; FMA8(m1, dw);
            dw = (double)wc2; FMA8(m2, dw);
            dw = (double)wc3; FMA8(m3, dw);
            dw = (double)wc4; FMA8(m4, dw);
            dw = (double)wc5; FMA8(m5, dw);
            dw = (double)wc6; FMA8(m6, dw);
            dw = (double)wc7; FMA8(m7, dw);
            wc0 = wn0; wc1 = wn1; wc2 = wn2; wc3 = wn3;
            wc4 = wn4; wc5 = wn5; wc6 = wn6; wc7 = wn7;
        }
    }

    h2g[(size_t)(b0 + 0) * 512 + nn] = a0;
    h2g[(size_t)(b0 + 1) * 512 + nn] = a1;
    h2g[(size_t)(b0 + 2) * 512 + nn] = a2;
    h2g[(size_t)(b0 + 3) * 512 + nn] = a3;
    h2g[(size_t)(b0 + 4) * 512 + nn] = a4;
    h2g[(size_t)(b0 + 5) * 512 + nn] = a5;
    h2g[(size_t)(b0 + 6) * 512 + nn] = a6;
    h2g[(size_t)(b0 + 7) * 512 + nn] = a7;
}

// ---------------- Gibbs chain: windowed, one wave per batch row --------------
// (exact revert to the best-measured round-8 version, 728 us)

#define LOADQ(NC, Q0, Q1, Q2, Q3) { \
    if ((NC) < N_H) { \
        const float4* p_ = (const float4*)(WHf + ((size_t)(NC) << 9) + (lane << 3)); \
        Q0 = p_[0]; Q1 = p_[1]; Q2 = Q1; Q3 = Q1; \
    } else { \
        const float4* p_ = (const float4*)(WOf + ((size_t)((NC) - N_H) << 10) + (lane << 4)); \
        Q0 = p_[0]; Q1 = p_[1]; Q2 = p_[2]; Q3 = p_[3]; \
    } }

#define APPLYQ(JC, NC, Q0, Q1, Q2, Q3) { \
    const double sd = ((A >> (JC)) & 1ull) ? 1.0 : -1.0; \
    if ((NC) < N_H) { \
        h2r[0] = fma(sd, (double)Q0.x, h2r[0]); \
        h2r[1] = fma(sd, (double)Q0.y, h2r[1]); \
        h2r[2] = fma(sd, (double)Q0.z, h2r[2]); \
        h2r[3] = fma(sd, (double)Q0.w, h2r[3]); \
        h2r[4] = fma(sd, (double)Q1.x, h2r[4]); \
        h2r[5] = fma(sd, (double)Q1.y, h2r[5]); \
        h2r[6] = fma(sd, (double)Q1.z, h2r[6]); \
        h2r[7] = fma(sd, (double)Q1.w, h2r[7]); \
    } else { \
        h1r[0]  = fma(sd, (double)Q0.x, h1r[0]); \
        h1r[1]  = fma(sd, (double)Q0.y, h1r[1]); \
        h1r[2]  = fma(sd, (double)Q0.z, h1r[2]); \
        h1r[3]  = fma(sd, (double)Q0.w, h1r[3]); \
        h1r[4]  = fma(sd, (double)Q1.x, h1r[4]); \
        h1r[5]  = fma(sd, (double)Q1.y, h1r[5]); \
        h1r[6]  = fma(sd, (double)Q1.z, h1r[6]); \
        h1r[7]  = fma(sd, (double)Q1.w, h1r[7]); \
        h1r[8]  = fma(sd, (double)Q2.x, h1r[8]); \
        h1r[9]  = fma(sd, (double)Q2.y, h1r[9]); \
        h1r[10] = fma(sd, (double)Q2.z, h1r[10]); \
        h1r[11] = fma(sd, (double)Q2.w, h1r[11]); \
        h1r[12] = fma(sd, (double)Q3.x, h1r[12]); \
        h1r[13] = fma(sd, (double)Q3.y, h1r[13]); \
        h1r[14] = fma(sd, (double)Q3.z, h1r[14]); \
        h1r[15] = fma(sd, (double)Q3.w, h1r[15]); \
    } }

#define DECLB(S) \
    int c##S = 0; \
    int j##S##0 = 0, j##S##1 = 0, j##S##2 = 0, j##S##3 = 0; \
    int n##S##0 = 0, n##S##1 = 0, n##S##2 = 0, n##S##3 = 0; \
    float4 S##q00, S##q01, S##q02, S##q03; \
    float4 S##q10, S##q11, S##q12, S##q13; \
    float4 S##q20, S##q21, S##q22, S##q23; \
    float4 S##q30, S##q31, S##q32, S##q33;

#define EXTRACTB(S) { \
    c##S = 0; \
    if (C) { \
        j##S##0 = __builtin_ctzll(C); C &= C - 1; \
        n##S##0 = __builtin_amdgcn_readlane(idw, j##S##0); \
        LOADQ(n##S##0, S##q00, S##q01, S##q02, S##q03); c##S = 1; \
        if (C) { \
            j##S##1 = __builtin_ctzll(C); C &= C - 1; \
            n##S##1 = __builtin_amdgcn_readlane(idw, j##S##1); \
            LOADQ(n##S##1, S##q10, S##q11, S##q12, S##q13); c##S = 2; \
            if (C) { \
                j##S##2 = __builtin_ctzll(C); C &= C - 1; \
                n##S##2 = __builtin_amdgcn_readlane(idw, j##S##2); \
                LOADQ(n##S##2, S##q20, S##q21, S##q22, S##q23); c##S = 3; \
                if (C) { \
                    j##S##3 = __builtin_ctzll(C); C &= C - 1; \
                    n##S##3 = __builtin_amdgcn_readlane(idw, j##S##3); \
                    LOADQ(n##S##3, S##q30, S##q31, S##q32, S##q33); c##S = 4; \
                } } } } }

#define APPLYB(S) { \
    APPLYQ(j##S##0, n##S##0, S##q00, S##q01, S##q02, S##q03); \
    if (c##S > 1) APPLYQ(j##S##1, n##S##1, S##q10, S##q11, S##q12, S##q13); \
    if (c##S > 2) APPLYQ(j##S##2, n##S##2, S##q20, S##q21, S##q22, S##q23); \
    if (c##S > 3) APPLYQ(j##S##3, n##S##3, S##q30, S##q31, S##q32, S##q33); }

__global__ __launch_bounds__(64, 2) void gibbs(
    const double* __restrict__ thT, const int* __restrict__ ids,
    const float* __restrict__ WHf, const float* __restrict__ WOf,
    const float* __restrict__ WXf,
    const int* __restrict__ pos2, const int* __restrict__ posB,
    const double* __restrict__ h1g, const double* __restrict__ h2g,
    const float* __restrict__ s1i, const float* __restrict__ s2i,
    float* __restrict__ out)
{
    const int lane = threadIdx.x;          // 0..63
    const int b = blockIdx.x;              // batch row

    __shared__ double fld[1536];                 // field mirror, unit-indexed
    __shared__ unsigned long long act[N_WIN];    // decision bits per window
    __shared__ unsigned long long sb[24];        // initial-state bits

    // master fields in registers: unit m = k*64 + lane  (nontemporal: read-once)
    double h1r[16], h2r[8];
    #pragma unroll
    for (int k = 0; k < 16; ++k)
        h1r[k] = __builtin_nontemporal_load(&h1g[(size_t)b * 1024 + k * 64 + lane]);
    #pragma unroll
    for (int k = 0; k < 8; ++k)
        h2r[k] = __builtin_nontemporal_load(&h2g[(size_t)b * 512 + k * 64 + lane]);

    // pack initial state into LDS bitmasks (nontemporal reads + ballots)
    #pragma unroll
    for (int k = 0; k < 16; ++k) {
        float v = __builtin_nontemporal_load(&s1i[(size_t)b * 1024 + k * 64 + lane]);
        unsigned long long m = __ballot(v != 0.0f);
        if (lane == 0) sb[k] = m;
    }
    #pragma unroll
    for (int k = 0; k < 8; ++k) {
        float v = __builtin_nontemporal_load(&s2i[(size_t)b * 512 + k * 64 + lane]);
        unsigned long long m = __ballot(v != 0.0f);
        if (lane == 0) sb[16 + k] = m;
    }

    // window-0 setup
    int idw = ids[lane];
    double thc = __builtin_nontemporal_load(&thT[(size_t)b * 3072 + lane]);
    int p2c = 0;

    for (int w = 0; w < N_WIN; ++w) {
        const int t0 = w * 64;

        // wx burst: this window's 64 couplings into registers (L2-cached table)
        const float* wxp = WXf + ((size_t)w << 12) + lane;
        float wx32[64];
        #pragma unroll
        for (int j = 0; j < 64; ++j) wx32[j] = wxp[(size_t)j * 64];

        // issue next-window loads early (consumed after the decision loop)
        int idn = 0; double thn = 0.0; int p2n = 0;
        if (w + 1 < N_WIN) {
            idn = ids[t0 + 64 + lane];
            thn = __builtin_nontemporal_load(&thT[(size_t)b * 3072 + t0 + 64 + lane]);
            if (w + 1 >= 24) p2n = pos2[(w + 1 - 24) * 64 + lane];
        }

        // old state of this window's unit
        int oldb;
        if (w < 24) {
            unsigned long long sv = sb[idw >> 6];
            oldb = (int)((sv >> (idw & 63)) & 1ull);
        } else {
            unsigned long long av = act[p2c >> 6];
            oldb = (int)((av >> (p2c & 63)) & 1ull);
        }
        unsigned long long OLD = __ballot(oldb != 0);

        // mirror master fields, gather decision scalar
        #pragma unroll
        for (int k = 0; k < 16; ++k) fld[k * 64 + lane] = h1r[k];
        #pragma unroll
        for (int k = 0; k < 8; ++k)  fld[1024 + k * 64 + lane] = h2r[k];
        double g = fld[idw];

        // decision loop: serial ALU chain
        unsigned long long A = 0;
        #pragma unroll
        for (int j = 0; j < 64; ++j) {
            unsigned long long bal = __ballot(g > thc);
            unsigned long long aj = (bal >> j) & 1ull;
            A |= aj << j;
            unsigned long long o = (OLD >> j) & 1ull;
            unsigned long long du = aj ? (o ? 0ull : 0x3FF0000000000000ull)
                                       : (o ? 0xBFF0000000000000ull : 0ull);
            g = fma(__builtin_bit_cast(double, du), (double)wx32[j], g);
        }
        if (lane == 0) act[w] = A;

        // ping-pong apply: chunk k+1's loads issue before chunk k's FMAs;
        // ascending-j order preserved (bit-identical). Skipped for the last
        // window: the output depends only on decision bits.
        if (w + 1 < N_WIN) {
            unsigned long long C = A ^ OLD;
            if (C) {
                DECLB(a)
                DECLB(b)
                EXTRACTB(a)
                for (;;) {
                    EXTRACTB(b)      // issue next chunk's loads
                    APPLYB(a)        // apply current chunk (a-count >= 1 here)
                    if (cb == 0) break;
                    EXTRACTB(a)      // issue next chunk's loads
                    APPLYB(b)
                    if (ca == 0) break;
                }
            }
        }

        idw = idn; thc = thn; p2c = p2n;
    }

    // epilogue: final states = sweep-2 decision bits (nontemporal stores)
    #pragma unroll
    for (int k = 0; k < 16; ++k) {
        int p = posB[k * 64 + lane];
        unsigned long long av = act[24 + (p >> 6)];
        __builtin_nontemporal_store((float)((av >> (p & 63)) & 1ull),
                                    &out[(size_t)b * 2560 + 1024 + k * 64 + lane]);
    }
    #pragma unroll
    for (int k = 0; k < 8; ++k) {
        int p = posB[1024 + k * 64 + lane];
        unsigned long long av = act[24 + (p >> 6)];
        __builtin_nontemporal_store((float)((av >> (p & 63)) & 1ull),
                                    &out[(size_t)b * 2560 + 2048 + k * 64 + lane]);
    }
}

// ---------------- launch ----------------
extern "C" void kernel_launch(void* const* d_in, const int* in_sizes, int n_in,
                              void* d_out, int out_size, void* d_ws, size_t ws_size,
                              hipStream_t stream) {
    const float* x   = (const float*)d_in[0];
    const float* s1i = (const float*)d_in[1];
    const float* s2i = (const float*)d_in[2];
    const float* W1  = (const float*)d_in[3];
    const float* b1  = (const float*)d_in[4];
    const float* W2  = (const float*)d_in[5];
    const float* b2  = (const float*)d_in[6];
    const float* u   = (const float*)d_in[7];
    const int*   ids = (const int*)d_in[8];
    float* out = (float*)d_out;

    char* ws = (char*)d_ws;
    float*  W1T  = (float*) (ws);                               //  4 MB
    float*  W2Tf = (float*) (ws + ((size_t)4  << 20));          //  2 MB
    float*  WHf  = (float*) (ws + ((size_t)6  << 20));          //  2 MB
    float*  WOf  = (float*) (ws + ((size_t)8  << 20));          //  2 MB
    float*  WXf  = (float*) (ws + ((size_t)10 << 20));          //  768 KB
    int*    posA = (int*)   (ws + ((size_t)11 << 20));          //  6 KB
    int*    posB = (int*)   (ws + ((size_t)11 << 20) + 8192);   //  6 KB
    int*    pos2 = (int*)   (ws + ((size_t)11 << 20) + 16384);  //  6 KB
    double* thT  = (double*)(ws + ((size_t)12 << 20));          // 48 MB
    double* h1g  = (double*)(ws + ((size_t)60 << 20));          // 16 MB
    double* h2g  = (double*)(ws + ((size_t)76 << 20));          //  8 MB (total 84 MB)

    hipLaunchKernelGGL(prep_w1t,  dim3(256),  dim3(256), 0, stream, W1, W1T);
    hipLaunchKernelGGL(prep_w2tf, dim3(128),  dim3(256), 0, stream, W2, W2Tf);
    hipLaunchKernelGGL(prep_whf,  dim3(2048), dim3(256), 0, stream, W2, WHf);
    hipLaunchKernelGGL(prep_wof,  dim3(2048), dim3(256), 0, stream, W2, WOf);
    hipLaunchKernelGGL(prep_wx,   dim3(768),  dim3(256), 0, stream, W2, ids, WXf);
    hipLaunchKernelGGL(prep_pos,  dim3(12),   dim3(256), 0, stream, ids, posA, posB);
    hipLaunchKernelGGL(prep_pos2, dim3(6),    dim3(256), 0, stream, ids, posA, pos2);
    hipLaunchKernelGGL(prep_th,   dim3(1536), dim3(256), 0, stream, u, thT);
    hipLaunchKernelGGL(copy_x,    dim3(2048), dim3(256), 0, stream, x, out);
    hipLaunchKernelGGL(init_h1,   dim3(512),  dim3(256), 0, stream,
                       x, s2i, W1T, W2, b1, h1g);
    hipLaunchKernelGGL(init_h2,   dim3(512),  dim3(256), 0, stream,
                       s1i, W2Tf, b2, h2g);
    hipLaunchKernelGGL(gibbs, dim3(2048), dim3(64), 0, stream,
                       thT, ids, WHf, WOf, WXf, pos2, posB, h1g, h2g, s1i, s2i, out);
}

// Round 11
// 1097.506 us; speedup vs baseline: 1.6143x; 1.0558x over previous
//
#include <hip/hip_runtime.h>
#include <math.h>

// Problem constants
#define B_TOT   2048
#define N_IN    1024
#define N_H     1024
#define N_OUT   512
#define N_UPD   1536
#define T_TOT   3072   // MAX_STEPS * N_UPD
#define N_WIN   48     // T_TOT / 64

// ---------------- prep kernels (consolidated) ----------------

// blocks 0..255: W1T[c*1024+r] = W1[r*1024+c]; blocks 256..383: W2Tf[c*512+r] = W2[r*1024+c]
__global__ __launch_bounds__(256) void prep_wt(const float* __restrict__ W1,
                                               const float* __restrict__ W2,
                                               float* __restrict__ W1T,
                                               float* __restrict__ W2Tf) {
    __shared__ float tile[64][65];
    int blk = blockIdx.x;
    int tx = threadIdx.x & 63;
    int ty0 = threadIdx.x >> 6;   // 0..3
    if (blk < 256) {
        int tc = blk & 15, tr = blk >> 4;
        for (int rr = ty0; rr < 64; rr += 4)
            tile[rr][tx] = W1[(size_t)(tr * 64 + rr) * 1024 + tc * 64 + tx];
        __syncthreads();
        for (int rr = ty0; rr < 64; rr += 4)
            W1T[(size_t)(tc * 64 + rr) * 1024 + tr * 64 + tx] = tile[tx][rr];
    } else {
        int b2 = blk - 256;               // 0..127
        int tc = b2 & 15, tr = b2 >> 4;   // tc 0..15 (cols of 1024), tr 0..7 (rows of 512)
        for (int rr = ty0; rr < 64; rr += 4)
            tile[rr][tx] = W2[(size_t)(tr * 64 + rr) * 1024 + tc * 64 + tx];
        __syncthreads();
        for (int rr = ty0; rr < 64; rr += 4)
            W2Tf[(size_t)(tc * 64 + rr) * 512 + tr * 64 + tx] = tile[tx][rr];
    }
}

// blocks 0..2047: WHf (from W2Tf, row-local reads)
// blocks 2048..4095: WOf; blocks 4096..4863: WXf
__global__ void prep_frag(const float* __restrict__ W2, const float* __restrict__ W2Tf,
                          const int* __restrict__ ids,
                          float* __restrict__ WHf, float* __restrict__ WOf,
                          float* __restrict__ WXf) {
    int blk = blockIdx.x;
    if (blk < 2048) {
        int idx = blk * 256 + threadIdx.x;    // < 1024*512
        int n = idx >> 9;
        int r = idx & 511;
        int l = r >> 3, j = r & 7;
        // WHf[n][l*8+j] = W2[(j*64+l)][n] = W2Tf[n*512 + j*64 + l]
        WHf[idx] = W2Tf[(size_t)n * 512 + j * 64 + l];
    } else if (blk < 4096) {
        int idx = (blk - 2048) * 256 + threadIdx.x;   // < 512*1024
        int nn = idx >> 10;
        int r = idx & 1023;
        int l = r >> 4, j = r & 15;
        WOf[idx] = W2[(size_t)nn * 1024 + j * 64 + l];
    } else {
        int idx = (blk - 4096) * 256 + threadIdx.x;   // < 48*4096
        int w = idx >> 12;
        int j = (idx >> 6) & 63;
        int l = idx & 63;
        int mj = ids[w * 64 + j];
        int nl = ids[w * 64 + l];
        float v = 0.0f;
        if (mj < N_H && nl >= N_H) v = W2[(size_t)(nl - N_H) * 1024 + mj];
        else if (mj >= N_H && nl < N_H) v = W2[(size_t)(mj - N_H) * 1024 + nl];
        WXf[idx] = v;
    }
}

// single block: posB[n], pos2[t] (posA kept in LDS; two phases with one barrier)
__global__ __launch_bounds__(1024) void prep_posall(const int* __restrict__ ids,
                                                    int* __restrict__ posB,
                                                    int* __restrict__ pos2) {
    __shared__ int pA[N_UPD];
    for (int t = threadIdx.x; t < T_TOT; t += 1024) {
        int n = ids[t];
        if (t < N_UPD) pA[n] = t; else posB[n] = t - N_UPD;
    }
    __syncthreads();
    for (int t = threadIdx.x; t < N_UPD; t += 1024)
        pos2[t] = pA[ids[N_UPD + t]];
}

// thT[b][t] = T(t) * (log(u[t][b]) - log1p(-u[t][b]))  in f64 — EXACT same
// expression/order as the previously-passing in-gibbs computation.
__global__ __launch_bounds__(256) void prep_th(const float* __restrict__ u,
                                               double* __restrict__ thT) {
    __shared__ double tile[64][65];
    int bt = blockIdx.x % 48;     // t tile
    int bb = blockIdx.x / 48;     // b tile
    int tx = threadIdx.x & 63;
    int ty0 = threadIdx.x >> 6;   // 0..3
    const double T1c = (double)(float)(2.0 / exp((double)1 / 5.0));
    for (int r = ty0; r < 64; r += 4) {
        int t = bt * 64 + r;
        double ud = (double)u[(size_t)t * 2048 + bb * 64 + tx];
        double T = (t >= N_UPD) ? T1c : 2.0;
        tile[r][tx] = T * (log(ud) - log1p(-ud));
    }
    __syncthreads();
    for (int r = ty0; r < 64; r += 4)
        thT[(size_t)(bb * 64 + r) * 3072 + bt * 64 + tx] = tile[tx][r];
}

// ---------------- init fields (fp64, merged h1+h2) ---------------------------
// Branch-free accumulate: acc_r = fma(bit?1.0:0.0, dw, acc_r) — bit-identical
// (fma(0,dw,a)==a; fma(1,dw,a)==a+dw, same ascending-input order).
// blocks 0..511: h1 (16 rows each); blocks 512..1023: h2 (8 rows each).

#define FMA16(M, DW) { \
    a0  = fma(((M) & 0x0001u) ? 1.0 : 0.0, (DW), a0 ); \
    a1  = fma(((M) & 0x0002u) ? 1.0 : 0.0, (DW), a1 ); \
    a2  = fma(((M) & 0x0004u) ? 1.0 : 0.0, (DW), a2 ); \
    a3  = fma(((M) & 0x0008u) ? 1.0 : 0.0, (DW), a3 ); \
    a4  = fma(((M) & 0x0010u) ? 1.0 : 0.0, (DW), a4 ); \
    a5  = fma(((M) & 0x0020u) ? 1.0 : 0.0, (DW), a5 ); \
    a6  = fma(((M) & 0x0040u) ? 1.0 : 0.0, (DW), a6 ); \
    a7  = fma(((M) & 0x0080u) ? 1.0 : 0.0, (DW), a7 ); \
    a8  = fma(((M) & 0x0100u) ? 1.0 : 0.0, (DW), a8 ); \
    a9  = fma(((M) & 0x0200u) ? 1.0 : 0.0, (DW), a9 ); \
    a10 = fma(((M) & 0x0400u) ? 1.0 : 0.0, (DW), a10); \
    a11 = fma(((M) & 0x0800u) ? 1.0 : 0.0, (DW), a11); \
    a12 = fma(((M) & 0x1000u) ? 1.0 : 0.0, (DW), a12); \
    a13 = fma(((M) & 0x2000u) ? 1.0 : 0.0, (DW), a13); \
    a14 = fma(((M) & 0x4000u) ? 1.0 : 0.0, (DW), a14); \
    a15 = fma(((M) & 0x8000u) ? 1.0 : 0.0, (DW), a15); }

#define FMA8(M, DW) { \
    a0 = fma(((M) & 0x01u) ? 1.0 : 0.0, (DW), a0); \
    a1 = fma(((M) & 0x02u) ? 1.0 : 0.0, (DW), a1); \
    a2 = fma(((M) & 0x04u) ? 1.0 : 0.0, (DW), a2); \
    a3 = fma(((M) & 0x08u) ? 1.0 : 0.0, (DW), a3); \
    a4 = fma(((M) & 0x10u) ? 1.0 : 0.0, (DW), a4); \
    a5 = fma(((M) & 0x20u) ? 1.0 : 0.0, (DW), a5); \
    a6 = fma(((M) & 0x40u) ? 1.0 : 0.0, (DW), a6); \
    a7 = fma(((M) & 0x80u) ? 1.0 : 0.0, (DW), a7); }

__global__ __launch_bounds__(256) void init_hh(
    const float* __restrict__ x, const float* __restrict__ s1i,
    const float* __restrict__ s2i,
    const float* __restrict__ W1T, const float* __restrict__ W2,
    const float* __restrict__ W2Tf,
    const float* __restrict__ b1, const float* __restrict__ b2,
    double* __restrict__ h1g, double* __restrict__ h2g)
{
    const int tid = threadIdx.x;
    __shared__ unsigned short xm[1024];
    __shared__ unsigned short s2m[512];

    if (blockIdx.x < 512) {
        // ---- h1: 16 rows per block ----
        const int ug  = blockIdx.x & 3;          // unit group (4 x 256)
        const int b0  = (blockIdx.x >> 2) << 4;  // row group base (16 rows)
        const int n   = (ug << 8) + tid;

        for (int i = tid; i < 1024; i += 256) {
            unsigned m = 0;
            #pragma unroll
            for (int bb = 0; bb < 16; ++bb)
                m |= (x[(size_t)(b0 + bb) * 1024 + i] != 0.0f) ? (1u << bb) : 0u;
            xm[i] = (unsigned short)m;
        }
        for (int j = tid; j < 512; j += 256) {
            unsigned m = 0;
            #pragma unroll
            for (int bb = 0; bb < 16; ++bb)
                m |= (s2i[(size_t)(b0 + bb) * 512 + j] != 0.0f) ? (1u << bb) : 0u;
            s2m[j] = (unsigned short)m;
        }
        __syncthreads();

        double a0, a1, a2, a3, a4, a5, a6, a7, a8, a9, a10, a11, a12, a13, a14, a15;
        {
            double bv = (double)b1[n];
            a0 = bv; a1 = bv; a2 = bv; a3 = bv; a4 = bv; a5 = bv; a6 = bv; a7 = bv;
            a8 = bv; a9 = bv; a10 = bv; a11 = bv; a12 = bv; a13 = bv; a14 = bv; a15 = bv;
        }

        // part 1: x @ W1^T, i ascending (1-group-deep weight prefetch)
        {
            float wc0, wc1, wc2, wc3, wc4, wc5, wc6, wc7;
            {
                const float* q = W1T + n;
                wc0 = q[0];    wc1 = q[1024]; wc2 = q[2048]; wc3 = q[3072];
                wc4 = q[4096]; wc5 = q[5120]; wc6 = q[6144]; wc7 = q[7168];
            }
            for (int i0 = 0; i0 < 1024; i0 += 8) {
                float wn0, wn1, wn2, wn3, wn4, wn5, wn6, wn7;
                if (i0 + 8 < 1024) {
                    const float* q = W1T + (size_t)(i0 + 8) * 1024 + n;
                    wn0 = q[0];    wn1 = q[1024]; wn2 = q[2048]; wn3 = q[3072];
                    wn4 = q[4096]; wn5 = q[5120]; wn6 = q[6144]; wn7 = q[7168];
                } else {
                    wn0 = wc0; wn1 = wc1; wn2 = wc2; wn3 = wc3;
                    wn4 = wc4; wn5 = wc5; wn6 = wc6; wn7 = wc7;
                }
                unsigned m0 = (unsigned)__builtin_amdgcn_readfirstlane((int)xm[i0 + 0]);
                unsigned m1 = (unsigned)__builtin_amdgcn_readfirstlane((int)xm[i0 + 1]);
                unsigned m2 = (unsigned)__builtin_amdgcn_readfirstlane((int)xm[i0 + 2]);
                unsigned m3 = (unsigned)__builtin_amdgcn_readfirstlane((int)xm[i0 + 3]);
                unsigned m4 = (unsigned)__builtin_amdgcn_readfirstlane((int)xm[i0 + 4]);
                unsigned m5 = (unsigned)__builtin_amdgcn_readfirstlane((int)xm[i0 + 5]);
                unsigned m6 = (unsigned)__builtin_amdgcn_readfirstlane((int)xm[i0 + 6]);
                unsigned m7 = (unsigned)__builtin_amdgcn_readfirstlane((int)xm[i0 + 7]);
                double dw;
                dw = (double)wc0; FMA16(m0, dw);
                dw = (double)wc1; FMA16(m1, dw);
                dw = (double)wc2; FMA16(m2, dw);
                dw = (double)wc3; FMA16(m3, dw);
                dw = (double)wc4; FMA16(m4, dw);
                dw = (double)wc5; FMA16(m5, dw);
                dw = (double)wc6; FMA16(m6, dw);
                dw = (double)wc7; FMA16(m7, dw);
                wc0 = wn0; wc1 = wn1; wc2 = wn2; wc3 = wn3;
                wc4 = wn4; wc5 = wn5; wc6 = wn6; wc7 = wn7;
            }
        }
        // part 2: s2 @ W2, o ascending
        {
            float wc0, wc1, wc2, wc3, wc4, wc5, wc6, wc7;
            {
                const float* q = W2 + n;
                wc0 = q[0];    wc1 = q[1024]; wc2 = q[2048]; wc3 = q[3072];
                wc4 = q[4096]; wc5 = q[5120]; wc6 = q[6144]; wc7 = q[7168];
            }
            for (int i0 = 0; i0 < 512; i0 += 8) {
                float wn0, wn1, wn2, wn3, wn4, wn5, wn6, wn7;
                if (i0 + 8 < 512) {
                    const float* q = W2 + (size_t)(i0 + 8) * 1024 + n;
                    wn0 = q[0];    wn1 = q[1024]; wn2 = q[2048]; wn3 = q[3072];
                    wn4 = q[4096]; wn5 = q[5120]; wn6 = q[6144]; wn7 = q[7168];
                } else {
                    wn0 = wc0; wn1 = wc1; wn2 = wc2; wn3 = wc3;
                    wn4 = wc4; wn5 = wc5; wn6 = wc6; wn7 = wc7;
                }
                unsigned m0 = (unsigned)__builtin_amdgcn_readfirstlane((int)s2m[i0 + 0]);
                unsigned m1 = (unsigned)__builtin_amdgcn_readfirstlane((int)s2m[i0 + 1]);
                unsigned m2 = (unsigned)__builtin_amdgcn_readfirstlane((int)s2m[i0 + 2]);
                unsigned m3 = (unsigned)__builtin_amdgcn_readfirstlane((int)s2m[i0 + 3]);
                unsigned m4 = (unsigned)__builtin_amdgcn_readfirstlane((int)s2m[i0 + 4]);
                unsigned m5 = (unsigned)__builtin_amdgcn_readfirstlane((int)s2m[i0 + 5]);
                unsigned m6 = (unsigned)__builtin_amdgcn_readfirstlane((int)s2m[i0 + 6]);
                unsigned m7 = (unsigned)__builtin_amdgcn_readfirstlane((int)s2m[i0 + 7]);
                double dw;
                dw = (double)wc0; FMA16(m0, dw);
                dw = (double)wc1; FMA16(m1, dw);
                dw = (double)wc2; FMA16(m2, dw);
                dw = (double)wc3; FMA16(m3, dw);
                dw = (double)wc4; FMA16(m4, dw);
                dw = (double)wc5; FMA16(m5, dw);
                dw = (double)wc6; FMA16(m6, dw);
                dw = (double)wc7; FMA16(m7, dw);
                wc0 = wn0; wc1 = wn1; wc2 = wn2; wc3 = wn3;
                wc4 = wn4; wc5 = wn5; wc6 = wn6; wc7 = wn7;
            }
        }

        h1g[(size_t)(b0 + 0)  * 1024 + n] = a0;
        h1g[(size_t)(b0 + 1)  * 1024 + n] = a1;
        h1g[(size_t)(b0 + 2)  * 1024 + n] = a2;
        h1g[(size_t)(b0 + 3)  * 1024 + n] = a3;
        h1g[(size_t)(b0 + 4)  * 1024 + n] = a4;
        h1g[(size_t)(b0 + 5)  * 1024 + n] = a5;
        h1g[(size_t)(b0 + 6)  * 1024 + n] = a6;
        h1g[(size_t)(b0 + 7)  * 1024 + n] = a7;
        h1g[(size_t)(b0 + 8)  * 1024 + n] = a8;
        h1g[(size_t)(b0 + 9)  * 1024 + n] = a9;
        h1g[(size_t)(b0 + 10) * 1024 + n] = a10;
        h1g[(size_t)(b0 + 11) * 1024 + n] = a11;
        h1g[(size_t)(b0 + 12) * 1024 + n] = a12;
        h1g[(size_t)(b0 + 13) * 1024 + n] = a13;
        h1g[(size_t)(b0 + 14) * 1024 + n] = a14;
        h1g[(size_t)(b0 + 15) * 1024 + n] = a15;
    } else {
        // ---- h2: 8 rows per block ----
        const int blk = blockIdx.x - 512;
        const int ug  = blk & 1;          // unit group (2 x 256)
        const int b0  = (blk >> 1) << 3;  // row group base (8 rows)
        const int nn  = (ug << 8) + tid;

        for (int i = tid; i < 1024; i += 256) {
            unsigned m = 0;
            #pragma unroll
            for (int bb = 0; bb < 8; ++bb)
                m |= (s1i[(size_t)(b0 + bb) * 1024 + i] != 0.0f) ? (1u << bb) : 0u;
            xm[i] = (unsigned short)m;
        }
        __syncthreads();

        double a0, a1, a2, a3, a4, a5, a6, a7;
        {
            double bv = (double)b2[nn];
            a0 = bv; a1 = bv; a2 = bv; a3 = bv; a4 = bv; a5 = bv; a6 = bv; a7 = bv;
        }

        {
            float wc0, wc1, wc2, wc3, wc4, wc5, wc6, wc7;
            {
                const float* q = W2Tf + nn;
                wc0 = q[0];    wc1 = q[512];  wc2 = q[1024]; wc3 = q[1536];
                wc4 = q[2048]; wc5 = q[2560]; wc6 = q[3072]; wc7 = q[3584];
            }
            for (int i0 = 0; i0 < 1024; i0 += 8) {
                float wn0, wn1, wn2, wn3, wn4, wn5, wn6, wn7;
                if (i0 + 8 < 1024) {
                    const float* q = W2Tf + (size_t)(i0 + 8) * 512 + nn;
                    wn0 = q[0];    wn1 = q[512];  wn2 = q[1024]; wn3 = q[1536];
                    wn4 = q[2048]; wn5 = q[2560]; wn6 = q[3072]; wn7 = q[3584];
                } else {
                    wn0 = wc0; wn1 = wc1; wn2 = wc2; wn3 = wc3;
                    wn4 = wc4; wn5 = wc5; wn6 = wc6; wn7 = wc7;
                }
                unsigned m0 = (unsigned)__builtin_amdgcn_readfirstlane((int)xm[i0 + 0]);
                unsigned m1 = (unsigned)__builtin_amdgcn_readfirstlane((int)xm[i0 + 1]);
                unsigned m2 = (unsigned)__builtin_amdgcn_readfirstlane((int)xm[i0 + 2]);
                unsigned m3 = (unsigned)__builtin_amdgcn_readfirstlane((int)xm[i0 + 3]);
                unsigned m4 = (unsigned)__builtin_amdgcn_readfirstlane((int)xm[i0 + 4]);
                unsigned m5 = (unsigned)__builtin_amdgcn_readfirstlane((int)xm[i0 + 5]);
                unsigned m6 = (unsigned)__builtin_amdgcn_readfirstlane((int)xm[i0 + 6]);
                unsigned m7 = (unsigned)__builtin_amdgcn_readfirstlane((int)xm[i0 + 7]);
                double dw;
                dw = (double)wc0; FMA8(m0, dw);
                dw = (double)wc1; FMA8(m1, dw);
                dw = (double)wc2; FMA8(m2, dw);
                dw = (double)wc3; FMA8(m3, dw);
                dw = (double)wc4; FMA8(m4, dw);
                dw = (double)wc5; FMA8(m5, dw);
                dw = (double)wc6; FMA8(m6, dw);
                dw = (double)wc7; FMA8(m7, dw);
                wc0 = wn0; wc1 = wn1; wc2 = wn2; wc3 = wn3;
                wc4 = wn4; wc5 = wn5; wc6 = wn6; wc7 = wn7;
            }
        }

        h2g[(size_t)(b0 + 0) * 512 + nn] = a0;
        h2g[(size_t)(b0 + 1) * 512 + nn] = a1;
        h2g[(size_t)(b0 + 2) * 512 + nn] = a2;
        h2g[(size_t)(b0 + 3) * 512 + nn] = a3;
        h2g[(size_t)(b0 + 4) * 512 + nn] = a4;
        h2g[(size_t)(b0 + 5) * 512 + nn] = a5;
        h2g[(size_t)(b0 + 6) * 512 + nn] = a6;
        h2g[(size_t)(b0 + 7) * 512 + nn] = a7;
    }
}

// ---------------- Gibbs chain: windowed, one wave per batch row --------------
// (gibbs core unchanged from the measured 727.8 us version; copy_x folded in)

#define LOADQ(NC, Q0, Q1, Q2, Q3) { \
    if ((NC) < N_H) { \
        const float4* p_ = (const float4*)(WHf + ((size_t)(NC) << 9) + (lane << 3)); \
        Q0 = p_[0]; Q1 = p_[1]; Q2 = Q1; Q3 = Q1; \
    } else { \
        const float4* p_ = (const float4*)(WOf + ((size_t)((NC) - N_H) << 10) + (lane << 4)); \
        Q0 = p_[0]; Q1 = p_[1]; Q2 = p_[2]; Q3 = p_[3]; \
    } }

#define APPLYQ(JC, NC, Q0, Q1, Q2, Q3) { \
    const double sd = ((A >> (JC)) & 1ull) ? 1.0 : -1.0; \
    if ((NC) < N_H) { \
        h2r[0] = fma(sd, (double)Q0.x, h2r[0]); \
        h2r[1] = fma(sd, (double)Q0.y, h2r[1]); \
        h2r[2] = fma(sd, (double)Q0.z, h2r[2]); \
        h2r[3] = fma(sd, (double)Q0.w, h2r[3]); \
        h2r[4] = fma(sd, (double)Q1.x, h2r[4]); \
        h2r[5] = fma(sd, (double)Q1.y, h2r[5]); \
        h2r[6] = fma(sd, (double)Q1.z, h2r[6]); \
        h2r[7] = fma(sd, (double)Q1.w, h2r[7]); \
    } else { \
        h1r[0]  = fma(sd, (double)Q0.x, h1r[0]); \
        h1r[1]  = fma(sd, (double)Q0.y, h1r[1]); \
        h1r[2]  = fma(sd, (double)Q0.z, h1r[2]); \
        h1r[3]  = fma(sd, (double)Q0.w, h1r[3]); \
        h1r[4]  = fma(sd, (double)Q1.x, h1r[4]); \
        h1r[5]  = fma(sd, (double)Q1.y, h1r[5]); \
        h1r[6]  = fma(sd, (double)Q1.z, h1r[6]); \
        h1r[7]  = fma(sd, (double)Q1.w, h1r[7]); \
        h1r[8]  = fma(sd, (double)Q2.x, h1r[8]); \
        h1r[9]  = fma(sd, (double)Q2.y, h1r[9]); \
        h1r[10] = fma(sd, (double)Q2.z, h1r[10]); \
        h1r[11] = fma(sd, (double)Q2.w, h1r[11]); \
        h1r[12] = fma(sd, (double)Q3.x, h1r[12]); \
        h1r[13] = fma(sd, (double)Q3.y, h1r[13]); \
        h1r[14] = fma(sd, (double)Q3.z, h1r[14]); \
        h1r[15] = fma(sd, (double)Q3.w, h1r[15]); \
    } }

#define DECLB(S) \
    int c##S = 0; \
    int j##S##0 = 0, j##S##1 = 0, j##S##2 = 0, j##S##3 = 0; \
    int n##S##0 = 0, n##S##1 = 0, n##S##2 = 0, n##S##3 = 0; \
    float4 S##q00, S##q01, S##q02, S##q03; \
    float4 S##q10, S##q11, S##q12, S##q13; \
    float4 S##q20, S##q21, S##q22, S##q23; \
    float4 S##q30, S##q31, S##q32, S##q33;

#define EXTRACTB(S) { \
    c##S = 0; \
    if (C) { \
        j##S##0 = __builtin_ctzll(C); C &= C - 1; \
        n##S##0 = __builtin_amdgcn_readlane(idw, j##S##0); \
        LOADQ(n##S##0, S##q00, S##q01, S##q02, S##q03); c##S = 1; \
        if (C) { \
            j##S##1 = __builtin_ctzll(C); C &= C - 1; \
            n##S##1 = __builtin_amdgcn_readlane(idw, j##S##1); \
            LOADQ(n##S##1, S##q10, S##q11, S##q12, S##q13); c##S = 2; \
            if (C) { \
                j##S##2 = __builtin_ctzll(C); C &= C - 1; \
                n##S##2 = __builtin_amdgcn_readlane(idw, j##S##2); \
                LOADQ(n##S##2, S##q20, S##q21, S##q22, S##q23); c##S = 3; \
                if (C) { \
                    j##S##3 = __builtin_ctzll(C); C &= C - 1; \
                    n##S##3 = __builtin_amdgcn_readlane(idw, j##S##3); \
                    LOADQ(n##S##3, S##q30, S##q31, S##q32, S##q33); c##S = 4; \
                } } } } }

#define APPLYB(S) { \
    APPLYQ(j##S##0, n##S##0, S##q00, S##q01, S##q02, S##q03); \
    if (c##S > 1) APPLYQ(j##S##1, n##S##1, S##q10, S##q11, S##q12, S##q13); \
    if (c##S > 2) APPLYQ(j##S##2, n##S##2, S##q20, S##q21, S##q22, S##q23); \
    if (c##S > 3) APPLYQ(j##S##3, n##S##3, S##q30, S##q31, S##q32, S##q33); }

__global__ __launch_bounds__(64, 2) void gibbs(
    const float* __restrict__ x,
    const double* __restrict__ thT, const int* __restrict__ ids,
    const float* __restrict__ WHf, const float* __restrict__ WOf,
    const float* __restrict__ WXf,
    const int* __restrict__ pos2, const int* __restrict__ posB,
    const double* __restrict__ h1g, const double* __restrict__ h2g,
    const float* __restrict__ s1i, const float* __restrict__ s2i,
    float* __restrict__ out)
{
    const int lane = threadIdx.x;          // 0..63
    const int b = blockIdx.x;              // batch row

    __shared__ double fld[1536];                 // field mirror, unit-indexed
    __shared__ unsigned long long act[N_WIN];    // decision bits per window
    __shared__ unsigned long long sb[24];        // initial-state bits

    // copy_x folded in: out[b][0:1024] = x[b][:]
    #pragma unroll
    for (int k = 0; k < 4; ++k) {
        float4 v = ((const float4*)(x + (size_t)b * 1024))[k * 64 + lane];
        ((float4*)(out + (size_t)b * 2560))[k * 64 + lane] = v;
    }

    // master fields in registers: unit m = k*64 + lane  (nontemporal: read-once)
    double h1r[16], h2r[8];
    #pragma unroll
    for (int k = 0; k < 16; ++k)
        h1r[k] = __builtin_nontemporal_load(&h1g[(size_t)b * 1024 + k * 64 + lane]);
    #pragma unroll
    for (int k = 0; k < 8; ++k)
        h2r[k] = __builtin_nontemporal_load(&h2g[(size_t)b * 512 + k * 64 + lane]);

    // pack initial state into LDS bitmasks (nontemporal reads + ballots)
    #pragma unroll
    for (int k = 0; k < 16; ++k) {
        float v = __builtin_nontemporal_load(&s1i[(size_t)b * 1024 + k * 64 + lane]);
        unsigned long long m = __ballot(v != 0.0f);
        if (lane == 0) sb[k] = m;
    }
    #pragma unroll
    for (int k = 0; k < 8; ++k) {
        float v = __builtin_nontemporal_load(&s2i[(size_t)b * 512 + k * 64 + lane]);
        unsigned long long m = __ballot(v != 0.0f);
        if (lane == 0) sb[16 + k] = m;
    }

    // window-0 setup
    int idw = ids[lane];
    double thc = __builtin_nontemporal_load(&thT[(size_t)b * 3072 + lane]);
    int p2c = 0;

    for (int w = 0; w < N_WIN; ++w) {
        const int t0 = w * 64;

        // wx burst: this window's 64 couplings into registers (L2-cached table)
        const float* wxp = WXf + ((size_t)w << 12) + lane;
        float wx32[64];
        #pragma unroll
        for (int j = 0; j < 64; ++j) wx32[j] = wxp[(size_t)j * 64];

        // issue next-window loads early (consumed after the decision loop)
        int idn = 0; double thn = 0.0; int p2n = 0;
        if (w + 1 < N_WIN) {
            idn = ids[t0 + 64 + lane];
            thn = __builtin_nontemporal_load(&thT[(size_t)b * 3072 + t0 + 64 + lane]);
            if (w + 1 >= 24) p2n = pos2[(w + 1 - 24) * 64 + lane];
        }

        // old state of this window's unit
        int oldb;
        if (w < 24) {
            unsigned long long sv = sb[idw >> 6];
            oldb = (int)((sv >> (idw & 63)) & 1ull);
        } else {
            unsigned long long av = act[p2c >> 6];
            oldb = (int)((av >> (p2c & 63)) & 1ull);
        }
        unsigned long long OLD = __ballot(oldb != 0);

        // mirror master fields, gather decision scalar
        #pragma unroll
        for (int k = 0; k < 16; ++k) fld[k * 64 + lane] = h1r[k];
        #pragma unroll
        for (int k = 0; k < 8; ++k)  fld[1024 + k * 64 + lane] = h2r[k];
        double g = fld[idw];

        // decision loop: serial ALU chain
        unsigned long long A = 0;
        #pragma unroll
        for (int j = 0; j < 64; ++j) {
            unsigned long long bal = __ballot(g > thc);
            unsigned long long aj = (bal >> j) & 1ull;
            A |= aj << j;
            unsigned long long o = (OLD >> j) & 1ull;
            unsigned long long du = aj ? (o ? 0ull : 0x3FF0000000000000ull)
                                       : (o ? 0xBFF0000000000000ull : 0ull);
            g = fma(__builtin_bit_cast(double, du), (double)wx32[j], g);
        }
        if (lane == 0) act[w] = A;

        // ping-pong apply: chunk k+1's loads issue before chunk k's FMAs;
        // ascending-j order preserved (bit-identical). Skipped for the last
        // window: the output depends only on decision bits.
        if (w + 1 < N_WIN) {
            unsigned long long C = A ^ OLD;
            if (C) {
                DECLB(a)
                DECLB(b)
                EXTRACTB(a)
                for (;;) {
                    EXTRACTB(b)      // issue next chunk's loads
                    APPLYB(a)        // apply current chunk (a-count >= 1 here)
                    if (cb == 0) break;
                    EXTRACTB(a)      // issue next chunk's loads
                    APPLYB(b)
                    if (ca == 0) break;
                }
            }
        }

        idw = idn; thc = thn; p2c = p2n;
    }

    // epilogue: final states = sweep-2 decision bits (nontemporal stores)
    #pragma unroll
    for (int k = 0; k < 16; ++k) {
        int p = posB[k * 64 + lane];
        unsigned long long av = act[24 + (p >> 6)];
        __builtin_nontemporal_store((float)((av >> (p & 63)) & 1ull),
                                    &out[(size_t)b * 2560 + 1024 + k * 64 + lane]);
    }
    #pragma unroll
    for (int k = 0; k < 8; ++k) {
        int p = posB[1024 + k * 64 + lane];
        unsigned long long av = act[24 + (p >> 6)];
        __builtin_nontemporal_store((float)((av >> (p & 63)) & 1ull),
                                    &out[(size_t)b * 2560 + 2048 + k * 64 + lane]);
    }
}

// ---------------- launch ----------------
extern "C" void kernel_launch(void* const* d_in, const int* in_sizes, int n_in,
                              void* d_out, int out_size, void* d_ws, size_t ws_size,
                              hipStream_t stream) {
    const float* x   = (const float*)d_in[0];
    const float* s1i = (const float*)d_in[1];
    const float* s2i = (const float*)d_in[2];
    const float* W1  = (const float*)d_in[3];
    const float* b1  = (const float*)d_in[4];
    const float* W2  = (const float*)d_in[5];
    const float* b2  = (const float*)d_in[6];
    const float* u   = (const float*)d_in[7];
    const int*   ids = (const int*)d_in[8];
    float* out = (float*)d_out;

    char* ws = (char*)d_ws;
    float*  W1T  = (float*) (ws);                               //  4 MB
    float*  W2Tf = (float*) (ws + ((size_t)4  << 20));          //  2 MB
    float*  WHf  = (float*) (ws + ((size_t)6  << 20));          //  2 MB
    float*  WOf  = (float*) (ws + ((size_t)8  << 20));          //  2 MB
    float*  WXf  = (float*) (ws + ((size_t)10 << 20));          //  768 KB
    int*    posB = (int*)   (ws + ((size_t)11 << 20) + 8192);   //  6 KB
    int*    pos2 = (int*)   (ws + ((size_t)11 << 20) + 16384);  //  6 KB
    double* thT  = (double*)(ws + ((size_t)12 << 20));          // 48 MB
    double* h1g  = (double*)(ws + ((size_t)60 << 20));          // 16 MB
    double* h2g  = (double*)(ws + ((size_t)76 << 20));          //  8 MB (total 84 MB)

    hipLaunchKernelGGL(prep_wt,     dim3(384),  dim3(256),  0, stream, W1, W2, W1T, W2Tf);
    hipLaunchKernelGGL(prep_frag,   dim3(4864), dim3(256),  0, stream, W2, W2Tf, ids, WHf, WOf, WXf);
    hipLaunchKernelGGL(prep_posall, dim3(1),    dim3(1024), 0, stream, ids, posB, pos2);
    hipLaunchKernelGGL(prep_th,     dim3(1536), dim3(256),  0, stream, u, thT);
    hipLaunchKernelGGL(init_hh,     dim3(1024), dim3(256),  0, stream,
                       x, s1i, s2i, W1T, W2, W2Tf, b1, b2, h1g, h2g);
    hipLaunchKernelGGL(gibbs,       dim3(2048), dim3(64),   0, stream,
                       x, thT, ids, WHf, WOf, WXf, pos2, posB, h1g, h2g, s1i, s2i, out);
}

// Round 12
// 1043.370 us; speedup vs baseline: 1.6980x; 1.0519x over previous
//
#include <hip/hip_runtime.h>
#include <math.h>

// Problem constants
#define B_TOT   2048
#define N_IN    1024
#define N_H     1024
#define N_OUT   512
#define N_UPD   1536
#define T_TOT   3072   // MAX_STEPS * N_UPD
#define N_WIN   48     // T_TOT / 64

// ---------------- prep stage 1: weight transposes ----------------

// blocks 0..255: W1T[c*1024+r] = W1[r*1024+c]; blocks 256..383: W2Tf[c*512+r] = W2[r*1024+c]
__global__ __launch_bounds__(256) void prep_wt(const float* __restrict__ W1,
                                               const float* __restrict__ W2,
                                               float* __restrict__ W1T,
                                               float* __restrict__ W2Tf) {
    __shared__ float tile[64][65];
    int blk = blockIdx.x;
    int tx = threadIdx.x & 63;
    int ty0 = threadIdx.x >> 6;   // 0..3
    if (blk < 256) {
        int tc = blk & 15, tr = blk >> 4;
        for (int rr = ty0; rr < 64; rr += 4)
            tile[rr][tx] = W1[(size_t)(tr * 64 + rr) * 1024 + tc * 64 + tx];
        __syncthreads();
        for (int rr = ty0; rr < 64; rr += 4)
            W1T[(size_t)(tc * 64 + rr) * 1024 + tr * 64 + tx] = tile[tx][rr];
    } else {
        int b2 = blk - 256;               // 0..127
        int tc = b2 & 15, tr = b2 >> 4;   // tc 0..15 (cols of 1024), tr 0..7 (rows of 512)
        for (int rr = ty0; rr < 64; rr += 4)
            tile[rr][tx] = W2[(size_t)(tr * 64 + rr) * 1024 + tc * 64 + tx];
        __syncthreads();
        for (int rr = ty0; rr < 64; rr += 4)
            W2Tf[(size_t)(tc * 64 + rr) * 512 + tr * 64 + tx] = tile[tx][rr];
    }
}

// ---------------- prep stage 2: everything else, one kernel ------------------
// blocks 0..1023   : init_hh   (h1: 0..511 at 16 rows; h2: 512..1023 at 8 rows)
// blocks 1024..2559: prep_th   (1536 tiles)
// blocks 2560..7423: prep_frag (WHf 2048 / WOf 2048 / WXf 768)
// block  7424      : posB/pos2
// Per-thread arithmetic identical to the previously verified kernels ->
// bit-identical outputs.

#define FMA16(M, DW) { \
    a0  = fma(((M) & 0x0001u) ? 1.0 : 0.0, (DW), a0 ); \
    a1  = fma(((M) & 0x0002u) ? 1.0 : 0.0, (DW), a1 ); \
    a2  = fma(((M) & 0x0004u) ? 1.0 : 0.0, (DW), a2 ); \
    a3  = fma(((M) & 0x0008u) ? 1.0 : 0.0, (DW), a3 ); \
    a4  = fma(((M) & 0x0010u) ? 1.0 : 0.0, (DW), a4 ); \
    a5  = fma(((M) & 0x0020u) ? 1.0 : 0.0, (DW), a5 ); \
    a6  = fma(((M) & 0x0040u) ? 1.0 : 0.0, (DW), a6 ); \
    a7  = fma(((M) & 0x0080u) ? 1.0 : 0.0, (DW), a7 ); \
    a8  = fma(((M) & 0x0100u) ? 1.0 : 0.0, (DW), a8 ); \
    a9  = fma(((M) & 0x0200u) ? 1.0 : 0.0, (DW), a9 ); \
    a10 = fma(((M) & 0x0400u) ? 1.0 : 0.0, (DW), a10); \
    a11 = fma(((M) & 0x0800u) ? 1.0 : 0.0, (DW), a11); \
    a12 = fma(((M) & 0x1000u) ? 1.0 : 0.0, (DW), a12); \
    a13 = fma(((M) & 0x2000u) ? 1.0 : 0.0, (DW), a13); \
    a14 = fma(((M) & 0x4000u) ? 1.0 : 0.0, (DW), a14); \
    a15 = fma(((M) & 0x8000u) ? 1.0 : 0.0, (DW), a15); }

#define FMA8(M, DW) { \
    a0 = fma(((M) & 0x01u) ? 1.0 : 0.0, (DW), a0); \
    a1 = fma(((M) & 0x02u) ? 1.0 : 0.0, (DW), a1); \
    a2 = fma(((M) & 0x04u) ? 1.0 : 0.0, (DW), a2); \
    a3 = fma(((M) & 0x08u) ? 1.0 : 0.0, (DW), a3); \
    a4 = fma(((M) & 0x10u) ? 1.0 : 0.0, (DW), a4); \
    a5 = fma(((M) & 0x20u) ? 1.0 : 0.0, (DW), a5); \
    a6 = fma(((M) & 0x40u) ? 1.0 : 0.0, (DW), a6); \
    a7 = fma(((M) & 0x80u) ? 1.0 : 0.0, (DW), a7); }

__global__ __launch_bounds__(256) void prep_mega(
    const float* __restrict__ x, const float* __restrict__ s1i,
    const float* __restrict__ s2i,
    const float* __restrict__ W1T, const float* __restrict__ W2,
    const float* __restrict__ W2Tf,
    const float* __restrict__ b1, const float* __restrict__ b2,
    double* __restrict__ h1g, double* __restrict__ h2g,
    const float* __restrict__ u, double* __restrict__ thT,
    const int* __restrict__ ids,
    float* __restrict__ WHf, float* __restrict__ WOf, float* __restrict__ WXf,
    int* __restrict__ posB, int* __restrict__ pos2)
{
    __shared__ __align__(16) char smraw[64 * 65 * 8];   // 33280 B, union of uses
    const int tid = threadIdx.x;
    const int blk = blockIdx.x;

    if (blk < 512) {
        // ---- init h1: 16 rows per block ----
        unsigned short* xm  = (unsigned short*)smraw;         // [1024]
        unsigned short* s2m = ((unsigned short*)smraw) + 1024; // [512]
        const int ug  = blk & 3;
        const int b0  = (blk >> 2) << 4;
        const int n   = (ug << 8) + tid;

        for (int i = tid; i < 1024; i += 256) {
            unsigned m = 0;
            #pragma unroll
            for (int bb = 0; bb < 16; ++bb)
                m |= (x[(size_t)(b0 + bb) * 1024 + i] != 0.0f) ? (1u << bb) : 0u;
            xm[i] = (unsigned short)m;
        }
        for (int j = tid; j < 512; j += 256) {
            unsigned m = 0;
            #pragma unroll
            for (int bb = 0; bb < 16; ++bb)
                m |= (s2i[(size_t)(b0 + bb) * 512 + j] != 0.0f) ? (1u << bb) : 0u;
            s2m[j] = (unsigned short)m;
        }
        __syncthreads();

        double a0, a1, a2, a3, a4, a5, a6, a7, a8, a9, a10, a11, a12, a13, a14, a15;
        {
            double bv = (double)b1[n];
            a0 = bv; a1 = bv; a2 = bv; a3 = bv; a4 = bv; a5 = bv; a6 = bv; a7 = bv;
            a8 = bv; a9 = bv; a10 = bv; a11 = bv; a12 = bv; a13 = bv; a14 = bv; a15 = bv;
        }

        // part 1: x @ W1^T, i ascending (1-group-deep weight prefetch)
        {
            float wc0, wc1, wc2, wc3, wc4, wc5, wc6, wc7;
            {
                const float* q = W1T + n;
                wc0 = q[0];    wc1 = q[1024]; wc2 = q[2048]; wc3 = q[3072];
                wc4 = q[4096]; wc5 = q[5120]; wc6 = q[6144]; wc7 = q[7168];
            }
            for (int i0 = 0; i0 < 1024; i0 += 8) {
                float wn0, wn1, wn2, wn3, wn4, wn5, wn6, wn7;
                if (i0 + 8 < 1024) {
                    const float* q = W1T + (size_t)(i0 + 8) * 1024 + n;
                    wn0 = q[0];    wn1 = q[1024]; wn2 = q[2048]; wn3 = q[3072];
                    wn4 = q[4096]; wn5 = q[5120]; wn6 = q[6144]; wn7 = q[7168];
                } else {
                    wn0 = wc0; wn1 = wc1; wn2 = wc2; wn3 = wc3;
                    wn4 = wc4; wn5 = wc5; wn6 = wc6; wn7 = wc7;
                }
                unsigned m0 = (unsigned)__builtin_amdgcn_readfirstlane((int)xm[i0 + 0]);
                unsigned m1 = (unsigned)__builtin_amdgcn_readfirstlane((int)xm[i0 + 1]);
                unsigned m2 = (unsigned)__builtin_amdgcn_readfirstlane((int)xm[i0 + 2]);
                unsigned m3 = (unsigned)__builtin_amdgcn_readfirstlane((int)xm[i0 + 3]);
                unsigned m4 = (unsigned)__builtin_amdgcn_readfirstlane((int)xm[i0 + 4]);
                unsigned m5 = (unsigned)__builtin_amdgcn_readfirstlane((int)xm[i0 + 5]);
                unsigned m6 = (unsigned)__builtin_amdgcn_readfirstlane((int)xm[i0 + 6]);
                unsigned m7 = (unsigned)__builtin_amdgcn_readfirstlane((int)xm[i0 + 7]);
                double dw;
                dw = (double)wc0; FMA16(m0, dw);
                dw = (double)wc1; FMA16(m1, dw);
                dw = (double)wc2; FMA16(m2, dw);
                dw = (double)wc3; FMA16(m3, dw);
                dw = (double)wc4; FMA16(m4, dw);
                dw = (double)wc5; FMA16(m5, dw);
                dw = (double)wc6; FMA16(m6, dw);
                dw = (double)wc7; FMA16(m7, dw);
                wc0 = wn0; wc1 = wn1; wc2 = wn2; wc3 = wn3;
                wc4 = wn4; wc5 = wn5; wc6 = wn6; wc7 = wn7;
            }
        }
        // part 2: s2 @ W2, o ascending
        {
            float wc0, wc1, wc2, wc3, wc4, wc5, wc6, wc7;
            {
                const float* q = W2 + n;
                wc0 = q[0];    wc1 = q[1024]; wc2 = q[2048]; wc3 = q[3072];
                wc4 = q[4096]; wc5 = q[5120]; wc6 = q[6144]; wc7 = q[7168];
            }
            for (int i0 = 0; i0 < 512; i0 += 8) {
                float wn0, wn1, wn2, wn3, wn4, wn5, wn6, wn7;
                if (i0 + 8 < 512) {
                    const float* q = W2 + (size_t)(i0 + 8) * 1024 + n;
                    wn0 = q[0];    wn1 = q[1024]; wn2 = q[2048]; wn3 = q[3072];
                    wn4 = q[4096]; wn5 = q[5120]; wn6 = q[6144]; wn7 = q[7168];
                } else {
                    wn0 = wc0; wn1 = wc1; wn2 = wc2; wn3 = wc3;
                    wn4 = wc4; wn5 = wc5; wn6 = wc6; wn7 = wc7;
                }
                unsigned m0 = (unsigned)__builtin_amdgcn_readfirstlane((int)s2m[i0 + 0]);
                unsigned m1 = (unsigned)__builtin_amdgcn_readfirstlane((int)s2m[i0 + 1]);
                unsigned m2 = (unsigned)__builtin_amdgcn_readfirstlane((int)s2m[i0 + 2]);
                unsigned m3 = (unsigned)__builtin_amdgcn_readfirstlane((int)s2m[i0 + 3]);
                unsigned m4 = (unsigned)__builtin_amdgcn_readfirstlane((int)s2m[i0 + 4]);
                unsigned m5 = (unsigned)__builtin_amdgcn_readfirstlane((int)s2m[i0 + 5]);
                unsigned m6 = (unsigned)__builtin_amdgcn_readfirstlane((int)s2m[i0 + 6]);
                unsigned m7 = (unsigned)__builtin_amdgcn_readfirstlane((int)s2m[i0 + 7]);
                double dw;
                dw = (double)wc0; FMA16(m0, dw);
                dw = (double)wc1; FMA16(m1, dw);
                dw = (double)wc2; FMA16(m2, dw);
                dw = (double)wc3; FMA16(m3, dw);
                dw = (double)wc4; FMA16(m4, dw);
                dw = (double)wc5; FMA16(m5, dw);
                dw = (double)wc6; FMA16(m6, dw);
                dw = (double)wc7; FMA16(m7, dw);
                wc0 = wn0; wc1 = wn1; wc2 = wn2; wc3 = wn3;
                wc4 = wn4; wc5 = wn5; wc6 = wn6; wc7 = wn7;
            }
        }

        h1g[(size_t)(b0 + 0)  * 1024 + n] = a0;
        h1g[(size_t)(b0 + 1)  * 1024 + n] = a1;
        h1g[(size_t)(b0 + 2)  * 1024 + n] = a2;
        h1g[(size_t)(b0 + 3)  * 1024 + n] = a3;
        h1g[(size_t)(b0 + 4)  * 1024 + n] = a4;
        h1g[(size_t)(b0 + 5)  * 1024 + n] = a5;
        h1g[(size_t)(b0 + 6)  * 1024 + n] = a6;
        h1g[(size_t)(b0 + 7)  * 1024 + n] = a7;
        h1g[(size_t)(b0 + 8)  * 1024 + n] = a8;
        h1g[(size_t)(b0 + 9)  * 1024 + n] = a9;
        h1g[(size_t)(b0 + 10) * 1024 + n] = a10;
        h1g[(size_t)(b0 + 11) * 1024 + n] = a11;
        h1g[(size_t)(b0 + 12) * 1024 + n] = a12;
        h1g[(size_t)(b0 + 13) * 1024 + n] = a13;
        h1g[(size_t)(b0 + 14) * 1024 + n] = a14;
        h1g[(size_t)(b0 + 15) * 1024 + n] = a15;
    } else if (blk < 1024) {
        // ---- init h2: 8 rows per block ----
        unsigned short* s1m = (unsigned short*)smraw;   // [1024]
        const int bb2 = blk - 512;
        const int ug  = bb2 & 1;
        const int b0  = (bb2 >> 1) << 3;
        const int nn  = (ug << 8) + tid;

        for (int i = tid; i < 1024; i += 256) {
            unsigned m = 0;
            #pragma unroll
            for (int bb = 0; bb < 8; ++bb)
                m |= (s1i[(size_t)(b0 + bb) * 1024 + i] != 0.0f) ? (1u << bb) : 0u;
            s1m[i] = (unsigned short)m;
        }
        __syncthreads();

        double a0, a1, a2, a3, a4, a5, a6, a7;
        {
            double bv = (double)b2[nn];
            a0 = bv; a1 = bv; a2 = bv; a3 = bv; a4 = bv; a5 = bv; a6 = bv; a7 = bv;
        }

        {
            float wc0, wc1, wc2, wc3, wc4, wc5, wc6, wc7;
            {
                const float* q = W2Tf + nn;
                wc0 = q[0];    wc1 = q[512];  wc2 = q[1024]; wc3 = q[1536];
                wc4 = q[2048]; wc5 = q[2560]; wc6 = q[3072]; wc7 = q[3584];
            }
            for (int i0 = 0; i0 < 1024; i0 += 8) {
                float wn0, wn1, wn2, wn3, wn4, wn5, wn6, wn7;
                if (i0 + 8 < 1024) {
                    const float* q = W2Tf + (size_t)(i0 + 8) * 512 + nn;
                    wn0 = q[0];    wn1 = q[512];  wn2 = q[1024]; wn3 = q[1536];
                    wn4 = q[2048]; wn5 = q[2560]; wn6 = q[3072]; wn7 = q[3584];
                } else {
                    wn0 = wc0; wn1 = wc1; wn2 = wc2; wn3 = wc3;
                    wn4 = wc4; wn5 = wc5; wn6 = wc6; wn7 = wc7;
                }
                unsigned m0 = (unsigned)__builtin_amdgcn_readfirstlane((int)s1m[i0 + 0]);
                unsigned m1 = (unsigned)__builtin_amdgcn_readfirstlane((int)s1m[i0 + 1]);
                unsigned m2 = (unsigned)__builtin_amdgcn_readfirstlane((int)s1m[i0 + 2]);
                unsigned m3 = (unsigned)__builtin_amdgcn_readfirstlane((int)s1m[i0 + 3]);
                unsigned m4 = (unsigned)__builtin_amdgcn_readfirstlane((int)s1m[i0 + 4]);
                unsigned m5 = (unsigned)__builtin_amdgcn_readfirstlane((int)s1m[i0 + 5]);
                unsigned m6 = (unsigned)__builtin_amdgcn_readfirstlane((int)s1m[i0 + 6]);
                unsigned m7 = (unsigned)__builtin_amdgcn_readfirstlane((int)s1m[i0 + 7]);
                double dw;
                dw = (double)wc0; FMA8(m0, dw);
                dw = (double)wc1; FMA8(m1, dw);
                dw = (double)wc2; FMA8(m2, dw);
                dw = (double)wc3; FMA8(m3, dw);
                dw = (double)wc4; FMA8(m4, dw);
                dw = (double)wc5; FMA8(m5, dw);
                dw = (double)wc6; FMA8(m6, dw);
                dw = (double)wc7; FMA8(m7, dw);
                wc0 = wn0; wc1 = wn1; wc2 = wn2; wc3 = wn3;
                wc4 = wn4; wc5 = wn5; wc6 = wn6; wc7 = wn7;
            }
        }

        h2g[(size_t)(b0 + 0) * 512 + nn] = a0;
        h2g[(size_t)(b0 + 1) * 512 + nn] = a1;
        h2g[(size_t)(b0 + 2) * 512 + nn] = a2;
        h2g[(size_t)(b0 + 3) * 512 + nn] = a3;
        h2g[(size_t)(b0 + 4) * 512 + nn] = a4;
        h2g[(size_t)(b0 + 5) * 512 + nn] = a5;
        h2g[(size_t)(b0 + 6) * 512 + nn] = a6;
        h2g[(size_t)(b0 + 7) * 512 + nn] = a7;
    } else if (blk < 2560) {
        // ---- prep_th tile (EXACT same expression/order as verified) ----
        double (*tile)[65] = (double(*)[65])smraw;
        const int pb = blk - 1024;
        int bt = pb % 48;
        int bb = pb / 48;
        int tx = tid & 63;
        int ty0 = tid >> 6;
        const double T1c = (double)(float)(2.0 / exp((double)1 / 5.0));
        for (int r = ty0; r < 64; r += 4) {
            int t = bt * 64 + r;
            double ud = (double)u[(size_t)t * 2048 + bb * 64 + tx];
            double T = (t >= N_UPD) ? T1c : 2.0;
            tile[r][tx] = T * (log(ud) - log1p(-ud));
        }
        __syncthreads();
        for (int r = ty0; r < 64; r += 4)
            thT[(size_t)(bb * 64 + r) * 3072 + bt * 64 + tx] = tile[tx][r];
    } else if (blk < 7424) {
        // ---- prep_frag ----
        const int fb = blk - 2560;
        if (fb < 2048) {
            int idx = fb * 256 + tid;             // < 1024*512
            int n = idx >> 9;
            int r = idx & 511;
            int l = r >> 3, j = r & 7;
            WHf[idx] = W2Tf[(size_t)n * 512 + j * 64 + l];
        } else if (fb < 4096) {
            int idx = (fb - 2048) * 256 + tid;    // < 512*1024
            int nn = idx >> 10;
            int r = idx & 1023;
            int l = r >> 4, j = r & 15;
            WOf[idx] = W2[(size_t)nn * 1024 + j * 64 + l];
        } else {
            int idx = (fb - 4096) * 256 + tid;    // < 48*4096
            int w = idx >> 12;
            int j = (idx >> 6) & 63;
            int l = idx & 63;
            int mj = ids[w * 64 + j];
            int nl = ids[w * 64 + l];
            float v = 0.0f;
            if (mj < N_H && nl >= N_H) v = W2[(size_t)(nl - N_H) * 1024 + mj];
            else if (mj >= N_H && nl < N_H) v = W2[(size_t)(mj - N_H) * 1024 + nl];
            WXf[idx] = v;
        }
    } else {
        // ---- posB / pos2 (single block) ----
        int* pA = (int*)smraw;   // [1536]
        for (int t = tid; t < T_TOT; t += 256) {
            int n = ids[t];
            if (t < N_UPD) pA[n] = t; else posB[n] = t - N_UPD;
        }
        __syncthreads();
        for (int t = tid; t < N_UPD; t += 256)
            pos2[t] = pA[ids[N_UPD + t]];
    }
}

// ---------------- Gibbs chain: windowed, one wave per batch row --------------
// (core unchanged from the measured 727.8 us version; copy_x folded in)

#define LOADQ(NC, Q0, Q1, Q2, Q3) { \
    if ((NC) < N_H) { \
        const float4* p_ = (const float4*)(WHf + ((size_t)(NC) << 9) + (lane << 3)); \
        Q0 = p_[0]; Q1 = p_[1]; Q2 = Q1; Q3 = Q1; \
    } else { \
        const float4* p_ = (const float4*)(WOf + ((size_t)((NC) - N_H) << 10) + (lane << 4)); \
        Q0 = p_[0]; Q1 = p_[1]; Q2 = p_[2]; Q3 = p_[3]; \
    } }

#define APPLYQ(JC, NC, Q0, Q1, Q2, Q3) { \
    const double sd = ((A >> (JC)) & 1ull) ? 1.0 : -1.0; \
    if ((NC) < N_H) { \
        h2r[0] = fma(sd, (double)Q0.x, h2r[0]); \
        h2r[1] = fma(sd, (double)Q0.y, h2r[1]); \
        h2r[2] = fma(sd, (double)Q0.z, h2r[2]); \
        h2r[3] = fma(sd, (double)Q0.w, h2r[3]); \
        h2r[4] = fma(sd, (double)Q1.x, h2r[4]); \
        h2r[5] = fma(sd, (double)Q1.y, h2r[5]); \
        h2r[6] = fma(sd, (double)Q1.z, h2r[6]); \
        h2r[7] = fma(sd, (double)Q1.w, h2r[7]); \
    } else { \
        h1r[0]  = fma(sd, (double)Q0.x, h1r[0]); \
        h1r[1]  = fma(sd, (double)Q0.y, h1r[1]); \
        h1r[2]  = fma(sd, (double)Q0.z, h1r[2]); \
        h1r[3]  = fma(sd, (double)Q0.w, h1r[3]); \
        h1r[4]  = fma(sd, (double)Q1.x, h1r[4]); \
        h1r[5]  = fma(sd, (double)Q1.y, h1r[5]); \
        h1r[6]  = fma(sd, (double)Q1.z, h1r[6]); \
        h1r[7]  = fma(sd, (double)Q1.w, h1r[7]); \
        h1r[8]  = fma(sd, (double)Q2.x, h1r[8]); \
        h1r[9]  = fma(sd, (double)Q2.y, h1r[9]); \
        h1r[10] = fma(sd, (double)Q2.z, h1r[10]); \
        h1r[11] = fma(sd, (double)Q2.w, h1r[11]); \
        h1r[12] = fma(sd, (double)Q3.x, h1r[12]); \
        h1r[13] = fma(sd, (double)Q3.y, h1r[13]); \
        h1r[14] = fma(sd, (double)Q3.z, h1r[14]); \
        h1r[15] = fma(sd, (double)Q3.w, h1r[15]); \
    } }

#define DECLB(S) \
    int c##S = 0; \
    int j##S##0 = 0, j##S##1 = 0, j##S##2 = 0, j##S##3 = 0; \
    int n##S##0 = 0, n##S##1 = 0, n##S##2 = 0, n##S##3 = 0; \
    float4 S##q00, S##q01, S##q02, S##q03; \
    float4 S##q10, S##q11, S##q12, S##q13; \
    float4 S##q20, S##q21, S##q22, S##q23; \
    float4 S##q30, S##q31, S##q32, S##q33;

#define EXTRACTB(S) { \
    c##S = 0; \
    if (C) { \
        j##S##0 = __builtin_ctzll(C); C &= C - 1; \
        n##S##0 = __builtin_amdgcn_readlane(idw, j##S##0); \
        LOADQ(n##S##0, S##q00, S##q01, S##q02, S##q03); c##S = 1; \
        if (C) { \
            j##S##1 = __builtin_ctzll(C); C &= C - 1; \
            n##S##1 = __builtin_amdgcn_readlane(idw, j##S##1); \
            LOADQ(n##S##1, S##q10, S##q11, S##q12, S##q13); c##S = 2; \
            if (C) { \
                j##S##2 = __builtin_ctzll(C); C &= C - 1; \
                n##S##2 = __builtin_amdgcn_readlane(idw, j##S##2); \
                LOADQ(n##S##2, S##q20, S##q21, S##q22, S##q23); c##S = 3; \
                if (C) { \
                    j##S##3 = __builtin_ctzll(C); C &= C - 1; \
                    n##S##3 = __builtin_amdgcn_readlane(idw, j##S##3); \
                    LOADQ(n##S##3, S##q30, S##q31, S##q32, S##q33); c##S = 4; \
                } } } } }

#define APPLYB(S) { \
    APPLYQ(j##S##0, n##S##0, S##q00, S##q01, S##q02, S##q03); \
    if (c##S > 1) APPLYQ(j##S##1, n##S##1, S##q10, S##q11, S##q12, S##q13); \
    if (c##S > 2) APPLYQ(j##S##2, n##S##2, S##q20, S##q21, S##q22, S##q23); \
    if (c##S > 3) APPLYQ(j##S##3, n##S##3, S##q30, S##q31, S##q32, S##q33); }

__global__ __launch_bounds__(64, 2) void gibbs(
    const float* __restrict__ x,
    const double* __restrict__ thT, const int* __restrict__ ids,
    const float* __restrict__ WHf, const float* __restrict__ WOf,
    const float* __restrict__ WXf,
    const int* __restrict__ pos2, const int* __restrict__ posB,
    const double* __restrict__ h1g, const double* __restrict__ h2g,
    const float* __restrict__ s1i, const float* __restrict__ s2i,
    float* __restrict__ out)
{
    const int lane = threadIdx.x;          // 0..63
    const int b = blockIdx.x;              // batch row

    __shared__ double fld[1536];                 // field mirror, unit-indexed
    __shared__ unsigned long long act[N_WIN];    // decision bits per window
    __shared__ unsigned long long sb[24];        // initial-state bits

    // copy_x folded in: out[b][0:1024] = x[b][:]
    #pragma unroll
    for (int k = 0; k < 4; ++k) {
        float4 v = ((const float4*)(x + (size_t)b * 1024))[k * 64 + lane];
        ((float4*)(out + (size_t)b * 2560))[k * 64 + lane] = v;
    }

    // master fields in registers: unit m = k*64 + lane  (nontemporal: read-once)
    double h1r[16], h2r[8];
    #pragma unroll
    for (int k = 0; k < 16; ++k)
        h1r[k] = __builtin_nontemporal_load(&h1g[(size_t)b * 1024 + k * 64 + lane]);
    #pragma unroll
    for (int k = 0; k < 8; ++k)
        h2r[k] = __builtin_nontemporal_load(&h2g[(size_t)b * 512 + k * 64 + lane]);

    // pack initial state into LDS bitmasks (nontemporal reads + ballots)
    #pragma unroll
    for (int k = 0; k < 16; ++k) {
        float v = __builtin_nontemporal_load(&s1i[(size_t)b * 1024 + k * 64 + lane]);
        unsigned long long m = __ballot(v != 0.0f);
        if (lane == 0) sb[k] = m;
    }
    #pragma unroll
    for (int k = 0; k < 8; ++k) {
        float v = __builtin_nontemporal_load(&s2i[(size_t)b * 512 + k * 64 + lane]);
        unsigned long long m = __ballot(v != 0.0f);
        if (lane == 0) sb[16 + k] = m;
    }

    // window-0 setup
    int idw = ids[lane];
    double thc = __builtin_nontemporal_load(&thT[(size_t)b * 3072 + lane]);
    int p2c = 0;

    for (int w = 0; w < N_WIN; ++w) {
        const int t0 = w * 64;

        // wx burst: this window's 64 couplings into registers (L2-cached table)
        const float* wxp = WXf + ((size_t)w << 12) + lane;
        float wx32[64];
        #pragma unroll
        for (int j = 0; j < 64; ++j) wx32[j] = wxp[(size_t)j * 64];

        // issue next-window loads early (consumed after the decision loop)
        int idn = 0; double thn = 0.0; int p2n = 0;
        if (w + 1 < N_WIN) {
            idn = ids[t0 + 64 + lane];
            thn = __builtin_nontemporal_load(&thT[(size_t)b * 3072 + t0 + 64 + lane]);
            if (w + 1 >= 24) p2n = pos2[(w + 1 - 24) * 64 + lane];
        }

        // old state of this window's unit
        int oldb;
        if (w < 24) {
            unsigned long long sv = sb[idw >> 6];
            oldb = (int)((sv >> (idw & 63)) & 1ull);
        } else {
            unsigned long long av = act[p2c >> 6];
            oldb = (int)((av >> (p2c & 63)) & 1ull);
        }
        unsigned long long OLD = __ballot(oldb != 0);

        // mirror master fields, gather decision scalar
        #pragma unroll
        for (int k = 0; k < 16; ++k) fld[k * 64 + lane] = h1r[k];
        #pragma unroll
        for (int k = 0; k < 8; ++k)  fld[1024 + k * 64 + lane] = h2r[k];
        double g = fld[idw];

        // decision loop: serial ALU chain
        unsigned long long A = 0;
        #pragma unroll
        for (int j = 0; j < 64; ++j) {
            unsigned long long bal = __ballot(g > thc);
            unsigned long long aj = (bal >> j) & 1ull;
            A |= aj << j;
            unsigned long long o = (OLD >> j) & 1ull;
            unsigned long long du = aj ? (o ? 0ull : 0x3FF0000000000000ull)
                                       : (o ? 0xBFF0000000000000ull : 0ull);
            g = fma(__builtin_bit_cast(double, du), (double)wx32[j], g);
        }
        if (lane == 0) act[w] = A;

        // ping-pong apply: chunk k+1's loads issue before chunk k's FMAs;
        // ascending-j order preserved (bit-identical). Skipped for the last
        // window: the output depends only on decision bits.
        if (w + 1 < N_WIN) {
            unsigned long long C = A ^ OLD;
            if (C) {
                DECLB(a)
                DECLB(b)
                EXTRACTB(a)
                for (;;) {
                    EXTRACTB(b)      // issue next chunk's loads
                    APPLYB(a)        // apply current chunk (a-count >= 1 here)
                    if (cb == 0) break;
                    EXTRACTB(a)      // issue next chunk's loads
                    APPLYB(b)
                    if (ca == 0) break;
                }
            }
        }

        idw = idn; thc = thn; p2c = p2n;
    }

    // epilogue: final states = sweep-2 decision bits (nontemporal stores)
    #pragma unroll
    for (int k = 0; k < 16; ++k) {
        int p = posB[k * 64 + lane];
        unsigned long long av = act[24 + (p >> 6)];
        __builtin_nontemporal_store((float)((av >> (p & 63)) & 1ull),
                                    &out[(size_t)b * 2560 + 1024 + k * 64 + lane]);
    }
    #pragma unroll
    for (int k = 0; k < 8; ++k) {
        int p = posB[1024 + k * 64 + lane];
        unsigned long long av = act[24 + (p >> 6)];
        __builtin_nontemporal_store((float)((av >> (p & 63)) & 1ull),
                                    &out[(size_t)b * 2560 + 2048 + k * 64 + lane]);
    }
}

// ---------------- launch ----------------
extern "C" void kernel_launch(void* const* d_in, const int* in_sizes, int n_in,
                              void* d_out, int out_size, void* d_ws, size_t ws_size,
                              hipStream_t stream) {
    const float* x   = (const float*)d_in[0];
    const float* s1i = (const float*)d_in[1];
    const float* s2i = (const float*)d_in[2];
    const float* W1  = (const float*)d_in[3];
    const float* b1  = (const float*)d_in[4];
    const float* W2  = (const float*)d_in[5];
    const float* b2  = (const float*)d_in[6];
    const float* u   = (const float*)d_in[7];
    const int*   ids = (const int*)d_in[8];
    float* out = (float*)d_out;

    char* ws = (char*)d_ws;
    float*  W1T  = (float*) (ws);                               //  4 MB
    float*  W2Tf = (float*) (ws + ((size_t)4  << 20));          //  2 MB
    float*  WHf  = (float*) (ws + ((size_t)6  << 20));          //  2 MB
    float*  WOf  = (float*) (ws + ((size_t)8  << 20));          //  2 MB
    float*  WXf  = (float*) (ws + ((size_t)10 << 20));          //  768 KB
    int*    posB = (int*)   (ws + ((size_t)11 << 20) + 8192);   //  6 KB
    int*    pos2 = (int*)   (ws + ((size_t)11 << 20) + 16384);  //  6 KB
    double* thT  = (double*)(ws + ((size_t)12 << 20));          // 48 MB
    double* h1g  = (double*)(ws + ((size_t)60 << 20));          // 16 MB
    double* h2g  = (double*)(ws + ((size_t)76 << 20));          //  8 MB (total 84 MB)

    hipLaunchKernelGGL(prep_wt,   dim3(384),  dim3(256), 0, stream, W1, W2, W1T, W2Tf);
    hipLaunchKernelGGL(prep_mega, dim3(7425), dim3(256), 0, stream,
                       x, s1i, s2i, W1T, W2, W2Tf, b1, b2, h1g, h2g,
                       u, thT, ids, WHf, WOf, WXf, posB, pos2);
    hipLaunchKernelGGL(gibbs,     dim3(2048), dim3(64),  0, stream,
                       x, thT, ids, WHf, WOf, WXf, pos2, posB, h1g, h2g, s1i, s2i, out);
}